// Round 7
// baseline (104.814 us; speedup 1.0000x reference)
//
#include <hip/hip_runtime.h>
#include <stdint.h>

// Problem constants
#define CH 8      // heads
#define CDH 64    // dim head
#define CB 2      // batch
#define CN 2048   // seq
#define CD 512    // model dim

typedef float f32x4 __attribute__((ext_vector_type(4)));
typedef __bf16 bf16x8 __attribute__((ext_vector_type(8)));
typedef unsigned short u16;

#define MFMA(a, b, c) __builtin_amdgcn_mfma_f32_16x16x32_bf16((a), (b), (c), 0, 0, 0)
#define GLOAD16(g, l)                                                              \
  __builtin_amdgcn_global_load_lds((const __attribute__((address_space(1))) void*)(g), \
                                   (__attribute__((address_space(3))) void*)(l), 16, 0, 0)

__device__ __forceinline__ u16 f2bf(float f) {
  union { float f; unsigned u; } c; c.f = f;
  return (u16)((c.u + 0x7FFFu + ((c.u >> 16) & 1u)) >> 16);
}
__device__ __forceinline__ u16 f2bf_hw(float f) {
  union { __bf16 h; u16 u; } c; c.h = (__bf16)f;
  return c.u;
}
__device__ __forceinline__ float bf2f(u16 h) {
  union { unsigned u; float f; } c; c.u = ((unsigned)h) << 16;
  return c.f;
}

// ---------------------------------------------------------------------------
// K0: LayerNorm over D=512 for q,k,v -> xln bf16 [3*4096][512]
// ---------------------------------------------------------------------------
__global__ __launch_bounds__(256) void ln_kernel(const float* __restrict__ q,
                                                 const float* __restrict__ k,
                                                 const float* __restrict__ v,
                                                 const float* __restrict__ g,
                                                 const float* __restrict__ bb,
                                                 u16* __restrict__ xln) {
  int row = blockIdx.x;                 // 0..12287
  int t = row >> 12;                    // /4096
  int rr = row & 4095;
  const float* src = (t == 0 ? q : (t == 1 ? k : v)) + (size_t)rr * CD;
  int tid = threadIdx.x;
  float x0 = src[tid], x1 = src[tid + 256];
  float s = x0 + x1, s2 = x0 * x0 + x1 * x1;
#pragma unroll
  for (int m = 1; m < 64; m <<= 1) { s += __shfl_xor(s, m); s2 += __shfl_xor(s2, m); }
  __shared__ float red[8];
  int w = tid >> 6;
  if ((tid & 63) == 0) { red[w] = s; red[4 + w] = s2; }
  __syncthreads();
  s = red[0] + red[1] + red[2] + red[3];
  s2 = red[4] + red[5] + red[6] + red[7];
  float mean = s * (1.f / 512.f);
  float var = s2 * (1.f / 512.f) - mean * mean;
  float rstd = rsqrtf(var + 1e-5f);
  u16* dst = xln + (size_t)row * CD;
  dst[tid]       = f2bf((x0 - mean) * rstd * g[tid] + bb[tid]);
  dst[tid + 256] = f2bf((x1 - mean) * rstd * g[tid + 256] + bb[tid + 256]);
}

// ---------------------------------------------------------------------------
// K0w: convert W_in, W_out to bf16
// ---------------------------------------------------------------------------
__global__ __launch_bounds__(256) void convw_kernel(const float* __restrict__ wi_f,
                                                    const float* __restrict__ wo_f,
                                                    u16* __restrict__ wi,
                                                    u16* __restrict__ wo) {
  int i = blockIdx.x * 256 + threadIdx.x;   // < 262144
  wi[i] = f2bf(wi_f[i]);
  wo[i] = f2bf(wo_f[i]);
}

// ---------------------------------------------------------------------------
// Generic C = A * Bt^T bf16 MFMA GEMM, K=512, BM=BN=128, BK=64, double-buffered
// ---------------------------------------------------------------------------
template <int OUT_BF16, int ADD_BIAS>
__global__ __launch_bounds__(256) void gemm_bt(const u16* __restrict__ A,
                                               const u16* __restrict__ Bt,
                                               void* __restrict__ Cout,
                                               const float* __restrict__ bias) {
  __shared__ u16 Al[2][128 * 64];
  __shared__ u16 Bl[2][128 * 64];
  int tm = blockIdx.x * 128, tn = blockIdx.y * 128;
  int tid = threadIdx.x;
  int w = tid >> 6, l = tid & 63;
  int wr = w >> 1, wc = w & 1;

  f32x4 zz = {0.f, 0.f, 0.f, 0.f};
  f32x4 acc[4][4];
#pragma unroll
  for (int mi = 0; mi < 4; mi++)
#pragma unroll
    for (int ni = 0; ni < 4; ni++) acc[mi][ni] = zz;

  int rowA = 8 * w + (l >> 3);
  int sl = l & 7;

#pragma unroll
  for (int i = 0; i < 4; i++) {
    int rl = rowA + 32 * i;
    int sp = sl ^ (rl & 7);
    GLOAD16(A + (size_t)(tm + rl) * CD + sp * 8, (char*)Al[0] + w * 1024 + i * 4096);
    GLOAD16(Bt + (size_t)(tn + rl) * CD + sp * 8, (char*)Bl[0] + w * 1024 + i * 4096);
  }
  __syncthreads();

  int cur = 0;
  for (int kt = 0; kt < 8; ++kt) {
    if (kt + 1 < 8) {
      int nxt = cur ^ 1;
#pragma unroll
      for (int i = 0; i < 4; i++) {
        int rl = rowA + 32 * i;
        int sp = sl ^ (rl & 7);
        GLOAD16(A + (size_t)(tm + rl) * CD + (kt + 1) * 64 + sp * 8,
                (char*)Al[nxt] + w * 1024 + i * 4096);
        GLOAD16(Bt + (size_t)(tn + rl) * CD + (kt + 1) * 64 + sp * 8,
                (char*)Bl[nxt] + w * 1024 + i * 4096);
      }
    }
    const u16* Ac = Al[cur];
    const u16* Bc = Bl[cur];
#pragma unroll
    for (int kk = 0; kk < 2; kk++) {
      bf16x8 af[4], bfr[4];
#pragma unroll
      for (int mi = 0; mi < 4; mi++) {
        int row = wr * 64 + mi * 16 + (l & 15);
        int slot = ((l >> 4) + 4 * kk) ^ (row & 7);
        af[mi] = *(const bf16x8*)&Ac[row * 64 + slot * 8];
      }
#pragma unroll
      for (int ni = 0; ni < 4; ni++) {
        int row = wc * 64 + ni * 16 + (l & 15);
        int slot = ((l >> 4) + 4 * kk) ^ (row & 7);
        bfr[ni] = *(const bf16x8*)&Bc[row * 64 + slot * 8];
      }
#pragma unroll
      for (int mi = 0; mi < 4; mi++)
#pragma unroll
        for (int ni = 0; ni < 4; ni++)
          acc[mi][ni] = MFMA(af[mi], bfr[ni], acc[mi][ni]);
    }
    if (kt + 1 < 8) {
      __syncthreads();
      cur ^= 1;
    }
  }
#pragma unroll
  for (int mi = 0; mi < 4; mi++)
#pragma unroll
    for (int ni = 0; ni < 4; ni++) {
      int col = tn + wc * 64 + ni * 16 + (l & 15);
      float bv = ADD_BIAS ? bias[col] : 0.f;
#pragma unroll
      for (int rg = 0; rg < 4; rg++) {
        int rowg = tm + wr * 64 + mi * 16 + (l >> 4) * 4 + rg;
        float vout = acc[mi][ni][rg] + bv;
        if (OUT_BF16)
          ((u16*)Cout)[(size_t)rowg * CD + col] = f2bf(vout);
        else
          ((float*)Cout)[(size_t)rowg * CD + col] = vout;
      }
    }
}

// ---------------------------------------------------------------------------
// K1b: transpose fv + rank-1 partial
// ---------------------------------------------------------------------------
__global__ __launch_bounds__(256) void transpose_v(const u16* __restrict__ F2,
                                                   const float* __restrict__ mk,
                                                   u16* __restrict__ fvT,
                                                   float* __restrict__ rpart) {
  int bid = blockIdx.x;
  int nt = bid & 31, b = (bid >> 5) & 1, h = bid >> 6;
  __shared__ u16 T[64 * 72];
  int tid = threadIdx.x;
  int n = tid >> 2;
#pragma unroll
  for (int p = 0; p < 2; p++) {
    int c = (tid & 3) + 4 * p;
    bf16x8 vv = *(const bf16x8*)&F2[((size_t)(b * CN + nt * 64 + n) * CD) + h * 64 + c * 8];
    *(bf16x8*)&T[n * 72 + c * 8] = vv;
  }
  __syncthreads();
  int d = tid >> 2;
#pragma unroll
  for (int p = 0; p < 2; p++) {
    int c = (tid & 3) + 4 * p;
    u16 tmp[8];
#pragma unroll
    for (int j = 0; j < 8; j++) tmp[j] = T[(c * 8 + j) * 72 + d];
    *(bf16x8*)&fvT[(((size_t)(h * 2 + b) * 64 + d) * CN) + nt * 64 + c * 8] =
        *(bf16x8*)tmp;
  }
  {
    int d2 = tid & 63, sub = tid >> 6;
    const float* mkp = mk + ((size_t)(h * 2 + b)) * CN + nt * 64;
    float s = 0.f;
#pragma unroll
    for (int i = 0; i < 16; i++) {
      int n2 = sub * 16 + i;
      s += mkp[n2] * bf2f(T[n2 * 72 + d2]);
    }
    __shared__ float rred[4][64];
    rred[sub][d2] = s;
    __syncthreads();
    if (sub == 0)
      rpart[(((size_t)(h * 2 + b)) * 32 + nt) * 64 + d2] =
          rred[0][d2] + rred[1][d2] + rred[2][d2] + rred[3][d2];
  }
}

// ---------------------------------------------------------------------------
// K1c: per-(h,b,n) stats
// ---------------------------------------------------------------------------
__global__ __launch_bounds__(256) void stats_kernel(const u16* __restrict__ F,
                                                    float* __restrict__ iqn,
                                                    float* __restrict__ mq,
                                                    float* __restrict__ ikn,
                                                    float* __restrict__ mk) {
  unsigned idx = blockIdx.x * 256 + threadIdx.x;
  int h = idx & 7;
  int n = (idx >> 3) & 2047;
  int b = (idx >> 14) & 1;
  int t = idx >> 15;
  const u16* p = F + ((size_t)(t * 4096 + b * CN + n)) * CD + h * 64;
  float s1 = 0.f, s2 = 0.f;
  const uint4* p4 = (const uint4*)p;
#pragma unroll
  for (int j = 0; j < 8; j++) {
    uint4 u = p4[j];
    unsigned arr[4] = {u.x, u.y, u.z, u.w};
#pragma unroll
    for (int e = 0; e < 4; e++) {
      float lo = bf2f((u16)(arr[e] & 0xFFFF));
      float hi = bf2f((u16)(arr[e] >> 16));
      s1 += lo + hi;
      s2 += lo * lo + hi * hi;
    }
  }
  float inv = 1.f / sqrtf(s2);
  float mean = s1 * (1.f / 64.f);
  size_t o = ((size_t)h * 2 + b) * CN + n;
  if (t == 0) { iqn[o] = inv; mq[o] = mean; }
  else        { ikn[o] = inv; mk[o] = mean; }
}

// ---------------------------------------------------------------------------
// K2a: partial sums of fq,fk over rows -> qgp/kgp [32ch][8h][64]
// ---------------------------------------------------------------------------
__global__ __launch_bounds__(256) void gsum_kernel(const u16* __restrict__ F0,
                                                   const u16* __restrict__ F1,
                                                   float* __restrict__ qgp,
                                                   float* __restrict__ kgp) {
  int h = blockIdx.x & 7, ch = blockIdx.x >> 3;
  int tid = threadIdx.x;
  int r0 = tid >> 3;
  int dc = (tid & 7) * 8;
  float aq[8], ak[8];
#pragma unroll
  for (int j = 0; j < 8; j++) { aq[j] = 0.f; ak[j] = 0.f; }
#pragma unroll
  for (int i = 0; i < 4; i++) {
    int row = ch * 128 + i * 32 + r0;
    bf16x8 vq = *(const bf16x8*)&F0[(size_t)row * CD + h * 64 + dc];
    bf16x8 vk = *(const bf16x8*)&F1[(size_t)row * CD + h * 64 + dc];
#pragma unroll
    for (int j = 0; j < 8; j++) { aq[j] += (float)vq[j]; ak[j] += (float)vk[j]; }
  }
  __shared__ float red[2][32][64];
#pragma unroll
  for (int j = 0; j < 8; j++) { red[0][r0][dc + j] = aq[j]; red[1][r0][dc + j] = ak[j]; }
  __syncthreads();
  if (tid < 64) {
    float sq = 0.f, sk = 0.f;
#pragma unroll
    for (int rr = 0; rr < 32; rr++) { sq += red[0][rr][tid]; sk += red[1][rr][tid]; }
    qgp[(ch * 8 + h) * 64 + tid] = sq;
    kgp[(ch * 8 + h) * 64 + tid] = sk;
  }
}

// ---------------------------------------------------------------------------
// K2f: finalize reductions + per-head blend MLP (merged), 1 block x 1024 thr
// ---------------------------------------------------------------------------
__global__ __launch_bounds__(1024) void finalize_mlp_kernel(
    const float* __restrict__ rpart, const float* __restrict__ qgp,
    const float* __restrict__ kgp, const float* __restrict__ w1,
    const float* __restrict__ b1, const float* __restrict__ lng,
    const float* __restrict__ lnb, const float* __restrict__ w2,
    const float* __restrict__ b2, float* __restrict__ rv,
    float* __restrict__ hp) {
  int o = threadIdx.x;
  int hb = o >> 6, d = o & 63;
  float s = 0.f;
#pragma unroll
  for (int nt = 0; nt < 32; nt++) s += rpart[((size_t)hb * 32 + nt) * 64 + d];
  rv[o] = s;
  __shared__ float qg[512], kg[512];
  if (o < 512) {
    int h = o >> 6, dd = o & 63;
    float s1 = 0.f, s2 = 0.f;
#pragma unroll
    for (int c = 0; c < 32; c++) {
      s1 += qgp[(c * 8 + h) * 64 + dd];
      s2 += kgp[(c * 8 + h) * 64 + dd];
    }
    qg[o] = s1 * (1.f / 4096.f);
    kg[o] = s2 * (1.f / 4096.f);
  }
  __syncthreads();
  if (o < 512) {
    int h = o >> 6, oo = o & 63;
    float acc = b1[oo];
#pragma unroll 8
    for (int i = 0; i < 64; i++)
      acc += qg[h * 64 + i] * w1[oo * 128 + i] + kg[h * 64 + i] * w1[oo * 128 + 64 + i];
    float s1 = acc, s2 = acc * acc;
#pragma unroll
    for (int m = 1; m < 64; m <<= 1) { s1 += __shfl_xor(s1, m); s2 += __shfl_xor(s2, m); }
    float mean = s1 * (1.f / 64.f);
    float var = s2 * (1.f / 64.f) - mean * mean;
    float y = (acc - mean) * rsqrtf(var + 1e-5f) * lng[oo] + lnb[oo];
    float hid = fmaxf(y, 0.f);
    float t = hid * w2[oo];
#pragma unroll
    for (int m = 1; m < 64; m <<= 1) t += __shfl_xor(t, m);
    float wv = 1.f / (1.f + expf(-(t + b2[0])));
    if (oo == 0) {
      hp[h * 4 + 0] = 1.f - wv;
      hp[h * 4 + 1] = wv * (1.f / 64.f);
      hp[h * 4 + 2] = wv;
    }
  }
}

// ---------------------------------------------------------------------------
// K3: streaming blended attention, M-SPLIT x2 for occupancy.
// grid 1024 (XCD-bijective 8x128); logical L: s=L>>9 (m half), qglob=L&511.
// Each block: 16 KV tiles, f32 partial O -> opart[s][qglob][64][64].
// R3 pipeline: STAGE(t+1) -> QKP(t) -> PV(t) -> barrier; K/V LDS dbuf.
// ---------------------------------------------------------------------------
__global__ __launch_bounds__(256) void attn_kernel(const u16* __restrict__ F0,
                                                   const u16* __restrict__ F1,
                                                   const u16* __restrict__ fvT,
                                                   const float* __restrict__ iqn,
                                                   const float* __restrict__ ikn,
                                                   const float* __restrict__ hp,
                                                   float* __restrict__ opart) {
  int lbid = (blockIdx.x & 7) * 128 + (blockIdx.x >> 3);
  int s = lbid >> 9;
  int qglob = lbid & 511;
  int qt = qglob & 31, b = (qglob >> 5) & 1, h = qglob >> 6;
  int tid = threadIdx.x, w = tid >> 6, l = tid & 63;
  float alpha = hp[h * 4 + 0], beta = hp[h * 4 + 1];

  __shared__ u16 Kl[2][64 * 64];   // K tiles (rows m, swizzled slots)
  __shared__ u16 Vl[2][64 * 64];   // V^T tiles (rows d, swizzled slots)
  __shared__ u16 Pl[64 * 72];      // P tile (wave-private rows)

  int qbase = qt * 64;
  int nloc = w * 16 + (l & 15);
  const u16* qp = F0 + ((size_t)(b * CN + qbase + nloc)) * CD + h * 64 + (l >> 4) * 8;
  bf16x8 aq0 = *(const bf16x8*)qp;
  bf16x8 aq1 = *(const bf16x8*)(qp + 32);

  const float* iqn_hb = iqn + ((size_t)h * 2 + b) * CN;
  const float* ikn_hb = ikn + ((size_t)h * 2 + b) * CN;
  float aqn[4];
#pragma unroll
  for (int rg = 0; rg < 4; rg++) {
    int nr = qbase + w * 16 + (l >> 4) * 4 + rg;
    aqn[rg] = alpha * iqn_hb[nr];
  }

  f32x4 zz = {0.f, 0.f, 0.f, 0.f};
  f32x4 oacc[4];
#pragma unroll
  for (int db = 0; db < 4; db++) oacc[db] = zz;

  const u16* Kg = F1 + (size_t)b * CN * CD + h * 64;
  const u16* Vg = fvT + ((size_t)h * 2 + b) * 64 * CN;

  int rls = 8 * w + (l >> 3);
  int sls = l & 7;

  float ikA[4], ikB[4];   // per-tile inv-k-norm prefetch (one tile ahead)

  auto STAGE = [&](int t, int slot) {
    int mb2 = t * 64;
#pragma unroll
    for (int i = 0; i < 2; i++) {
      int row = rls + 32 * i;
      int sp = sls ^ (row & 7);
      GLOAD16(Kg + (size_t)(mb2 + row) * CD + sp * 8,
              (char*)Kl[slot] + w * 1024 + i * 4096);
      GLOAD16(Vg + (size_t)row * CN + mb2 + sp * 8,
              (char*)Vl[slot] + w * 1024 + i * 4096);
    }
  };
  auto LOADIK = [&](float (&ik)[4], int t) {
    int mbase = t * 64;
#pragma unroll
    for (int mb = 0; mb < 4; mb++) ik[mb] = ikn_hb[mbase + mb * 16 + (l & 15)];
  };
  auto QKP = [&](const u16* Kc, const float (&ik)[4]) {
#pragma unroll
    for (int mb = 0; mb < 4; mb++) {
      int rowk = mb * 16 + (l & 15);
      int c0 = (l >> 4) ^ (rowk & 7);
      int c1 = ((l >> 4) + 4) ^ (rowk & 7);
      bf16x8 bk0 = *(const bf16x8*)&Kc[rowk * 64 + c0 * 8];
      bf16x8 bk1 = *(const bf16x8*)&Kc[rowk * 64 + c1 * 8];
      f32x4 dacc = zz;
      dacc = MFMA(aq0, bk0, dacc);
      dacc = MFMA(aq1, bk1, dacc);
#pragma unroll
      for (int rg = 0; rg < 4; rg++) {
        float pv = dacc[rg] * (aqn[rg] * ik[mb] + beta);
        Pl[(w * 16 + (l >> 4) * 4 + rg) * 72 + mb * 16 + (l & 15)] = f2bf_hw(pv);
      }
    }
  };
  auto PV = [&](const u16* Vc) {
#pragma unroll
    for (int c = 0; c < 2; c++) {
      bf16x8 ap = *(const bf16x8*)&Pl[(w * 16 + (l & 15)) * 72 + (l >> 4) * 8 + c * 32];
#pragma unroll
      for (int db = 0; db < 4; db++) {
        int rowd = db * 16 + (l & 15);
        int ck = ((l >> 4) + 4 * c) ^ (rowd & 7);
        bf16x8 bv = *(const bf16x8*)&Vc[rowd * 64 + ck * 8];
        oacc[db] = MFMA(ap, bv, oacc[db]);
      }
    }
  };

  int t0 = s * 16;   // this split's KV-tile range: [t0, t0+16)

  // prologue: first tile into buf 0
  STAGE(t0, 0);
  LOADIK(ikA, t0);
  __syncthreads();   // implicit vmcnt(0): tile t0 resident

  for (int t = t0; t < t0 + 16; t += 2) {
    // even tile t (buf 0): issue next tile's loads first, then compute
    STAGE(t + 1, 1);          // t+1 <= t0+15 always
    LOADIK(ikB, t + 1);
    QKP(Kl[0], ikA);
    PV(Vl[0]);
    __syncthreads();

    // odd tile t+1 (buf 1)
    if (t + 2 < t0 + 16) {
      STAGE(t + 2, 0);
      LOADIK(ikA, t + 2);
    }
    QKP(Kl[1], ikB);
    PV(Vl[1]);
    __syncthreads();
  }

  // epilogue: f32 partial store (rank-1 correction applied in reduce_o)
  float* op = opart + ((size_t)s * 512 + qglob) * 4096;
#pragma unroll
  for (int db = 0; db < 4; db++) {
    int dcol = db * 16 + (l & 15);
#pragma unroll
    for (int rg = 0; rg < 4; rg++) {
      int r = w * 16 + (l >> 4) * 4 + rg;
      op[r * 64 + dcol] = oacc[db][rg];
    }
  }
}

// ---------------------------------------------------------------------------
// K3b: reduce the two m-split partials + rank-1 correction -> A2 bf16
// grid 512 (qglob), 256 threads
// ---------------------------------------------------------------------------
__global__ __launch_bounds__(256) void reduce_o(const float* __restrict__ opart,
                                                const float* __restrict__ mq,
                                                const float* __restrict__ hp,
                                                const float* __restrict__ rv,
                                                u16* __restrict__ A2) {
  int qglob = blockIdx.x;
  int qt = qglob & 31, b = (qglob >> 5) & 1, h = qglob >> 6;
  int tid = threadIdx.x;
  int r = tid >> 2;              // 0..63
  int c0 = (tid & 3) * 16;       // 0,16,32,48
  int n = qt * 64 + r;
  float gamma = hp[h * 4 + 2];
  float mqg = gamma * mq[((size_t)h * 2 + b) * CN + n];
  const float* p0 = opart + (size_t)qglob * 4096 + r * 64 + c0;
  const float* p1 = opart + ((size_t)512 + qglob) * 4096 + r * 64 + c0;
  const float* rh = rv + ((size_t)h * 2 + b) * 64 + c0;
  u16* dst = A2 + ((size_t)(b * CN + n)) * CD + h * 64 + c0;
#pragma unroll
  for (int jc = 0; jc < 4; jc++) {
    f32x4 a = *(const f32x4*)&p0[jc * 4];
    f32x4 bq = *(const f32x4*)&p1[jc * 4];
    f32x4 rr = *(const f32x4*)&rh[jc * 4];
#pragma unroll
    for (int e = 0; e < 4; e++)
      dst[jc * 4 + e] = f2bf(a[e] + bq[e] - mqg * rr[e]);
  }
}

// ---------------------------------------------------------------------------
extern "C" void kernel_launch(void* const* d_in, const int* in_sizes, int n_in,
                              void* d_out, int out_size, void* d_ws, size_t ws_size,
                              hipStream_t stream) {
  const float* q = (const float*)d_in[0];
  const float* k = (const float*)d_in[1];
  const float* v = (const float*)d_in[2];
  const float* ln_g = (const float*)d_in[3];
  const float* ln_b = (const float*)d_in[4];
  const float* W_in = (const float*)d_in[5];
  const float* wp_w1 = (const float*)d_in[6];
  const float* wp_b1 = (const float*)d_in[7];
  const float* wp_lng = (const float*)d_in[8];
  const float* wp_lnb = (const float*)d_in[9];
  const float* wp_w2 = (const float*)d_in[10];
  const float* wp_b2 = (const float*)d_in[11];
  const float* W_out = (const float*)d_in[12];
  const float* b_out = (const float*)d_in[13];

  char* ws = (char*)d_ws;
  u16* xln = (u16*)(ws + 0);              // 12,582,912 B
  u16* F = (u16*)(ws + 12582912);         // 12,582,912 B  [3][B][N][512]
  u16* Wi = (u16*)(ws + 25165824);        // 524,288 B
  u16* Wo = (u16*)(ws + 25690112);        // 524,288 B
  u16* fvT = (u16*)(ws + 26214400);       // 4,194,304 B   [H][B][64][2048]
  u16* A2 = (u16*)(ws + 30408704);        // 4,194,304 B   [B][N][512]
  float* iqn = (float*)(ws + 34603008);   // 131,072 B each
  float* mq = (float*)(ws + 34734080);
  float* ikn = (float*)(ws + 34865152);
  float* mk = (float*)(ws + 34996224);
  float* qgp = (float*)(ws + 35127296);   // 65,536 B
  float* kgp = (float*)(ws + 35192832);   // 65,536 B
  float* hp = (float*)(ws + 35258368);    // 128 B
  float* rv = (float*)(ws + 35258496);    // 4,096 B
  float* rpart = (float*)(ws + 35262592); // 131,072 B
  float* opart = (float*)(ws + 35393664); // 16,777,216 B  [2][512][64][64] f32

  u16* F0 = F;
  u16* F1 = F + 2097152;
  u16* F2 = F + 4194304;

  ln_kernel<<<12288, 256, 0, stream>>>(q, k, v, ln_g, ln_b, xln);
  convw_kernel<<<1024, 256, 0, stream>>>(W_in, W_out, Wi, Wo);
  gemm_bt<1, 0><<<dim3(96, 4), 256, 0, stream>>>(xln, Wi, (void*)F, nullptr);
  stats_kernel<<<256, 256, 0, stream>>>(F, iqn, mq, ikn, mk);
  transpose_v<<<512, 256, 0, stream>>>(F2, mk, fvT, rpart);
  gsum_kernel<<<256, 256, 0, stream>>>(F0, F1, qgp, kgp);
  finalize_mlp_kernel<<<1, 1024, 0, stream>>>(rpart, qgp, kgp, wp_w1, wp_b1,
                                              wp_lng, wp_lnb, wp_w2, wp_b2, rv, hp);
  attn_kernel<<<1024, 256, 0, stream>>>(F0, F1, fvT, iqn, ikn, hp, opart);
  reduce_o<<<512, 256, 0, stream>>>(opart, mq, hp, rv, A2);
  gemm_bt<0, 1><<<dim3(32, 4), 256, 0, stream>>>(A2, Wo, d_out, b_out);
}

// Round 8
// 94.980 us; speedup vs baseline: 1.1035x; 1.1035x over previous
//
#include <hip/hip_runtime.h>
#include <stdint.h>

// Problem constants
#define CH 8      // heads
#define CDH 64    // dim head
#define CB 2      // batch
#define CN 2048   // seq
#define CD 512    // model dim

typedef float f32x4 __attribute__((ext_vector_type(4)));
typedef __bf16 bf16x8 __attribute__((ext_vector_type(8)));
typedef unsigned short u16;

#define MFMA(a, b, c) __builtin_amdgcn_mfma_f32_16x16x32_bf16((a), (b), (c), 0, 0, 0)
#define GLOAD16(g, l)                                                              \
  __builtin_amdgcn_global_load_lds((const __attribute__((address_space(1))) void*)(g), \
                                   (__attribute__((address_space(3))) void*)(l), 16, 0, 0)

__device__ __forceinline__ u16 f2bf(float f) {
  union { float f; unsigned u; } c; c.f = f;
  return (u16)((c.u + 0x7FFFu + ((c.u >> 16) & 1u)) >> 16);
}
__device__ __forceinline__ u16 f2bf_hw(float f) {
  union { __bf16 h; u16 u; } c; c.h = (__bf16)f;
  return c.u;
}
__device__ __forceinline__ float bf2f(u16 h) {
  union { unsigned u; float f; } c; c.u = ((unsigned)h) << 16;
  return c.f;
}

// ---------------------------------------------------------------------------
// K0: LayerNorm over D=512 for q,k,v -> xln bf16 [3*4096][512]
// ---------------------------------------------------------------------------
__global__ __launch_bounds__(256) void ln_kernel(const float* __restrict__ q,
                                                 const float* __restrict__ k,
                                                 const float* __restrict__ v,
                                                 const float* __restrict__ g,
                                                 const float* __restrict__ bb,
                                                 u16* __restrict__ xln) {
  int row = blockIdx.x;                 // 0..12287
  int t = row >> 12;                    // /4096
  int rr = row & 4095;
  const float* src = (t == 0 ? q : (t == 1 ? k : v)) + (size_t)rr * CD;
  int tid = threadIdx.x;
  float x0 = src[tid], x1 = src[tid + 256];
  float s = x0 + x1, s2 = x0 * x0 + x1 * x1;
#pragma unroll
  for (int m = 1; m < 64; m <<= 1) { s += __shfl_xor(s, m); s2 += __shfl_xor(s2, m); }
  __shared__ float red[8];
  int w = tid >> 6;
  if ((tid & 63) == 0) { red[w] = s; red[4 + w] = s2; }
  __syncthreads();
  s = red[0] + red[1] + red[2] + red[3];
  s2 = red[4] + red[5] + red[6] + red[7];
  float mean = s * (1.f / 512.f);
  float var = s2 * (1.f / 512.f) - mean * mean;
  float rstd = rsqrtf(var + 1e-5f);
  u16* dst = xln + (size_t)row * CD;
  dst[tid]       = f2bf((x0 - mean) * rstd * g[tid] + bb[tid]);
  dst[tid + 256] = f2bf((x1 - mean) * rstd * g[tid + 256] + bb[tid + 256]);
}

// ---------------------------------------------------------------------------
// K0w: convert W_in, W_out to bf16
// ---------------------------------------------------------------------------
__global__ __launch_bounds__(256) void convw_kernel(const float* __restrict__ wi_f,
                                                    const float* __restrict__ wo_f,
                                                    u16* __restrict__ wi,
                                                    u16* __restrict__ wo) {
  int i = blockIdx.x * 256 + threadIdx.x;   // < 262144
  wi[i] = f2bf(wi_f[i]);
  wo[i] = f2bf(wo_f[i]);
}

// ---------------------------------------------------------------------------
// Generic C = A * Bt^T bf16 MFMA GEMM, K=512, BM=BN=128, BK=64, double-buffered
// ---------------------------------------------------------------------------
template <int OUT_BF16, int ADD_BIAS>
__global__ __launch_bounds__(256) void gemm_bt(const u16* __restrict__ A,
                                               const u16* __restrict__ Bt,
                                               void* __restrict__ Cout,
                                               const float* __restrict__ bias) {
  __shared__ u16 Al[2][128 * 64];
  __shared__ u16 Bl[2][128 * 64];
  int tm = blockIdx.x * 128, tn = blockIdx.y * 128;
  int tid = threadIdx.x;
  int w = tid >> 6, l = tid & 63;
  int wr = w >> 1, wc = w & 1;

  f32x4 zz = {0.f, 0.f, 0.f, 0.f};
  f32x4 acc[4][4];
#pragma unroll
  for (int mi = 0; mi < 4; mi++)
#pragma unroll
    for (int ni = 0; ni < 4; ni++) acc[mi][ni] = zz;

  int rowA = 8 * w + (l >> 3);
  int sl = l & 7;

#pragma unroll
  for (int i = 0; i < 4; i++) {
    int rl = rowA + 32 * i;
    int sp = sl ^ (rl & 7);
    GLOAD16(A + (size_t)(tm + rl) * CD + sp * 8, (char*)Al[0] + w * 1024 + i * 4096);
    GLOAD16(Bt + (size_t)(tn + rl) * CD + sp * 8, (char*)Bl[0] + w * 1024 + i * 4096);
  }
  __syncthreads();

  int cur = 0;
  for (int kt = 0; kt < 8; ++kt) {
    if (kt + 1 < 8) {
      int nxt = cur ^ 1;
#pragma unroll
      for (int i = 0; i < 4; i++) {
        int rl = rowA + 32 * i;
        int sp = sl ^ (rl & 7);
        GLOAD16(A + (size_t)(tm + rl) * CD + (kt + 1) * 64 + sp * 8,
                (char*)Al[nxt] + w * 1024 + i * 4096);
        GLOAD16(Bt + (size_t)(tn + rl) * CD + (kt + 1) * 64 + sp * 8,
                (char*)Bl[nxt] + w * 1024 + i * 4096);
      }
    }
    const u16* Ac = Al[cur];
    const u16* Bc = Bl[cur];
#pragma unroll
    for (int kk = 0; kk < 2; kk++) {
      bf16x8 af[4], bfr[4];
#pragma unroll
      for (int mi = 0; mi < 4; mi++) {
        int row = wr * 64 + mi * 16 + (l & 15);
        int slot = ((l >> 4) + 4 * kk) ^ (row & 7);
        af[mi] = *(const bf16x8*)&Ac[row * 64 + slot * 8];
      }
#pragma unroll
      for (int ni = 0; ni < 4; ni++) {
        int row = wc * 64 + ni * 16 + (l & 15);
        int slot = ((l >> 4) + 4 * kk) ^ (row & 7);
        bfr[ni] = *(const bf16x8*)&Bc[row * 64 + slot * 8];
      }
#pragma unroll
      for (int mi = 0; mi < 4; mi++)
#pragma unroll
        for (int ni = 0; ni < 4; ni++)
          acc[mi][ni] = MFMA(af[mi], bfr[ni], acc[mi][ni]);
    }
    if (kt + 1 < 8) {
      __syncthreads();
      cur ^= 1;
    }
  }
#pragma unroll
  for (int mi = 0; mi < 4; mi++)
#pragma unroll
    for (int ni = 0; ni < 4; ni++) {
      int col = tn + wc * 64 + ni * 16 + (l & 15);
      float bv = ADD_BIAS ? bias[col] : 0.f;
#pragma unroll
      for (int rg = 0; rg < 4; rg++) {
        int rowg = tm + wr * 64 + mi * 16 + (l >> 4) * 4 + rg;
        float vout = acc[mi][ni][rg] + bv;
        if (OUT_BF16)
          ((u16*)Cout)[(size_t)rowg * CD + col] = f2bf(vout);
        else
          ((float*)Cout)[(size_t)rowg * CD + col] = vout;
      }
    }
}

// ---------------------------------------------------------------------------
// K1b: transpose fv + rank-1 partial
// ---------------------------------------------------------------------------
__global__ __launch_bounds__(256) void transpose_v(const u16* __restrict__ F2,
                                                   const float* __restrict__ mk,
                                                   u16* __restrict__ fvT,
                                                   float* __restrict__ rpart) {
  int bid = blockIdx.x;
  int nt = bid & 31, b = (bid >> 5) & 1, h = bid >> 6;
  __shared__ u16 T[64 * 72];
  int tid = threadIdx.x;
  int n = tid >> 2;
#pragma unroll
  for (int p = 0; p < 2; p++) {
    int c = (tid & 3) + 4 * p;
    bf16x8 vv = *(const bf16x8*)&F2[((size_t)(b * CN + nt * 64 + n) * CD) + h * 64 + c * 8];
    *(bf16x8*)&T[n * 72 + c * 8] = vv;
  }
  __syncthreads();
  int d = tid >> 2;
#pragma unroll
  for (int p = 0; p < 2; p++) {
    int c = (tid & 3) + 4 * p;
    u16 tmp[8];
#pragma unroll
    for (int j = 0; j < 8; j++) tmp[j] = T[(c * 8 + j) * 72 + d];
    *(bf16x8*)&fvT[(((size_t)(h * 2 + b) * 64 + d) * CN) + nt * 64 + c * 8] =
        *(bf16x8*)tmp;
  }
  {
    int d2 = tid & 63, sub = tid >> 6;
    const float* mkp = mk + ((size_t)(h * 2 + b)) * CN + nt * 64;
    float s = 0.f;
#pragma unroll
    for (int i = 0; i < 16; i++) {
      int n2 = sub * 16 + i;
      s += mkp[n2] * bf2f(T[n2 * 72 + d2]);
    }
    __shared__ float rred[4][64];
    rred[sub][d2] = s;
    __syncthreads();
    if (sub == 0)
      rpart[(((size_t)(h * 2 + b)) * 32 + nt) * 64 + d2] =
          rred[0][d2] + rred[1][d2] + rred[2][d2] + rred[3][d2];
  }
}

// ---------------------------------------------------------------------------
// K1c: merged stats + global partial sums (single pass over F0,F1).
// grid 256 (h:3 low | ch:5), 256 threads.
// Per row: inv-norm + mean of q,k head slices. Per block: column sums.
// ---------------------------------------------------------------------------
__global__ __launch_bounds__(256) void statsum_kernel(const u16* __restrict__ F0,
                                                      const u16* __restrict__ F1,
                                                      float* __restrict__ iqn,
                                                      float* __restrict__ mq,
                                                      float* __restrict__ ikn,
                                                      float* __restrict__ mk,
                                                      float* __restrict__ qgp,
                                                      float* __restrict__ kgp) {
  int h = blockIdx.x & 7, ch = blockIdx.x >> 3;   // ch in [0,32)
  int tid = threadIdx.x;
  int r0 = tid >> 3;          // 0..31
  int dcx = tid & 7;
  int dc = dcx * 8;
  float aq[8], ak[8];
#pragma unroll
  for (int j = 0; j < 8; j++) { aq[j] = 0.f; ak[j] = 0.f; }
#pragma unroll
  for (int i = 0; i < 4; i++) {
    int row = ch * 128 + i * 32 + r0;   // global row in [0,4096)
    bf16x8 vq = *(const bf16x8*)&F0[(size_t)row * CD + h * 64 + dc];
    bf16x8 vk = *(const bf16x8*)&F1[(size_t)row * CD + h * 64 + dc];
    float s1q = 0.f, s2q = 0.f, s1k = 0.f, s2k = 0.f;
#pragma unroll
    for (int j = 0; j < 8; j++) {
      float fq = (float)vq[j], fk = (float)vk[j];
      aq[j] += fq; ak[j] += fk;
      s1q += fq; s2q += fq * fq;
      s1k += fk; s2k += fk * fk;
    }
    // reduce across the 8 lanes sharing this row (lanes r0*8 .. r0*8+7)
#pragma unroll
    for (int m = 1; m < 8; m <<= 1) {
      s1q += __shfl_xor(s1q, m); s2q += __shfl_xor(s2q, m);
      s1k += __shfl_xor(s1k, m); s2k += __shfl_xor(s2k, m);
    }
    if (dcx == 0) {
      int b = row >> 11, n = row & 2047;
      size_t o = ((size_t)h * 2 + b) * CN + n;
      iqn[o] = 1.f / sqrtf(s2q);
      mq[o] = s1q * (1.f / 64.f);
      ikn[o] = 1.f / sqrtf(s2k);
      mk[o] = s1k * (1.f / 64.f);
    }
  }
  __shared__ float red[2][32][64];
#pragma unroll
  for (int j = 0; j < 8; j++) { red[0][r0][dc + j] = aq[j]; red[1][r0][dc + j] = ak[j]; }
  __syncthreads();
  if (tid < 64) {
    float sq = 0.f, sk = 0.f;
#pragma unroll
    for (int rr = 0; rr < 32; rr++) { sq += red[0][rr][tid]; sk += red[1][rr][tid]; }
    qgp[(ch * 8 + h) * 64 + tid] = sq;
    kgp[(ch * 8 + h) * 64 + tid] = sk;
  }
}

// ---------------------------------------------------------------------------
// K2f: finalize reductions + per-head blend MLP (merged), 1 block x 1024 thr
// ---------------------------------------------------------------------------
__global__ __launch_bounds__(1024) void finalize_mlp_kernel(
    const float* __restrict__ rpart, const float* __restrict__ qgp,
    const float* __restrict__ kgp, const float* __restrict__ w1,
    const float* __restrict__ b1, const float* __restrict__ lng,
    const float* __restrict__ lnb, const float* __restrict__ w2,
    const float* __restrict__ b2, float* __restrict__ rv,
    float* __restrict__ hp) {
  int o = threadIdx.x;
  int hb = o >> 6, d = o & 63;
  float s = 0.f;
#pragma unroll
  for (int nt = 0; nt < 32; nt++) s += rpart[((size_t)hb * 32 + nt) * 64 + d];
  rv[o] = s;
  __shared__ float qg[512], kg[512];
  if (o < 512) {
    int h = o >> 6, dd = o & 63;
    float s1 = 0.f, s2 = 0.f;
#pragma unroll
    for (int c = 0; c < 32; c++) {
      s1 += qgp[(c * 8 + h) * 64 + dd];
      s2 += kgp[(c * 8 + h) * 64 + dd];
    }
    qg[o] = s1 * (1.f / 4096.f);
    kg[o] = s2 * (1.f / 4096.f);
  }
  __syncthreads();
  if (o < 512) {
    int h = o >> 6, oo = o & 63;
    float acc = b1[oo];
#pragma unroll 8
    for (int i = 0; i < 64; i++)
      acc += qg[h * 64 + i] * w1[oo * 128 + i] + kg[h * 64 + i] * w1[oo * 128 + 64 + i];
    float s1 = acc, s2 = acc * acc;
#pragma unroll
    for (int m = 1; m < 64; m <<= 1) { s1 += __shfl_xor(s1, m); s2 += __shfl_xor(s2, m); }
    float mean = s1 * (1.f / 64.f);
    float var = s2 * (1.f / 64.f) - mean * mean;
    float y = (acc - mean) * rsqrtf(var + 1e-5f) * lng[oo] + lnb[oo];
    float hid = fmaxf(y, 0.f);
    float t = hid * w2[oo];
#pragma unroll
    for (int m = 1; m < 64; m <<= 1) t += __shfl_xor(t, m);
    float wv = 1.f / (1.f + expf(-(t + b2[0])));
    if (oo == 0) {
      hp[h * 4 + 0] = 1.f - wv;
      hp[h * 4 + 1] = wv * (1.f / 64.f);
      hp[h * 4 + 2] = wv;
    }
  }
}

// ---------------------------------------------------------------------------
// K3: streaming blended attention, QT=128 (2 row-frags/wave) + m-split x2.
// grid 512 (XCD-bijective 8x64): s = L>>8 (m half), qg128 = L&255.
// K/V tile reads amortized over 2x output rows -> ~1.5x fewer LDS instrs
// per MFMA (the R7-diagnosed bottleneck). P tile XOR-swizzled.
// ---------------------------------------------------------------------------
__global__ __launch_bounds__(256) void attn_kernel(const u16* __restrict__ F0,
                                                   const u16* __restrict__ F1,
                                                   const u16* __restrict__ fvT,
                                                   const float* __restrict__ iqn,
                                                   const float* __restrict__ ikn,
                                                   const float* __restrict__ hp,
                                                   float* __restrict__ opart) {
  int lbid = (blockIdx.x & 7) * 64 + (blockIdx.x >> 3);   // bijective, 512=8*64
  int s = lbid >> 8;
  int qg128 = lbid & 255;
  int qt = qg128 & 15;
  int hb = qg128 >> 4;
  int b = hb & 1, h = hb >> 1;
  int tid = threadIdx.x, w = tid >> 6, l = tid & 63;
  float alpha = hp[h * 4 + 0], beta = hp[h * 4 + 1];

  __shared__ u16 Kl[2][64 * 64];   // K tiles (rows m, swizzled slots)
  __shared__ u16 Vl[2][64 * 64];   // V^T tiles (rows d, swizzled slots)
  __shared__ u16 Pl[128 * 72];     // P tile (wave-private 32-row bands), swizzled

  int qbase = qt * 128;
  int lo = l & 15, hi = l >> 4;

  // Q fragments: 2 row-frags x 2 k-halves
  bf16x8 aq[2][2];
#pragma unroll
  for (int f = 0; f < 2; f++) {
    int nq = qbase + w * 32 + f * 16 + lo;
    const u16* qp = F0 + ((size_t)(b * CN + nq)) * CD + h * 64 + hi * 8;
    aq[f][0] = *(const bf16x8*)qp;
    aq[f][1] = *(const bf16x8*)(qp + 32);
  }

  const float* iqn_hb = iqn + ((size_t)h * 2 + b) * CN;
  const float* ikn_hb = ikn + ((size_t)h * 2 + b) * CN;
  float aqn[2][4];
#pragma unroll
  for (int f = 0; f < 2; f++)
#pragma unroll
    for (int rg = 0; rg < 4; rg++) {
      int nr = qbase + w * 32 + f * 16 + hi * 4 + rg;
      aqn[f][rg] = alpha * iqn_hb[nr];
    }

  f32x4 zz = {0.f, 0.f, 0.f, 0.f};
  f32x4 oacc[2][4];
#pragma unroll
  for (int f = 0; f < 2; f++)
#pragma unroll
    for (int db = 0; db < 4; db++) oacc[f][db] = zz;

  const u16* Kg = F1 + (size_t)b * CN * CD + h * 64;
  const u16* Vg = fvT + ((size_t)h * 2 + b) * 64 * CN;

  int rls = 8 * w + (l >> 3);
  int sls = l & 7;

  float ikA[4], ikB[4];

  auto STAGE = [&](int t, int slot) {
    int mb2 = t * 64;
#pragma unroll
    for (int i = 0; i < 2; i++) {
      int row = rls + 32 * i;
      int sp = sls ^ (row & 7);
      GLOAD16(Kg + (size_t)(mb2 + row) * CD + sp * 8,
              (char*)Kl[slot] + w * 1024 + i * 4096);
      GLOAD16(Vg + (size_t)row * CN + mb2 + sp * 8,
              (char*)Vl[slot] + w * 1024 + i * 4096);
    }
  };
  auto LOADIK = [&](float (&ik)[4], int t) {
    int mbase = t * 64;
#pragma unroll
    for (int mb = 0; mb < 4; mb++) ik[mb] = ikn_hb[mbase + mb * 16 + lo];
  };
  auto QKP = [&](const u16* Kc, const float (&ik)[4]) {
#pragma unroll
    for (int mb = 0; mb < 4; mb++) {
      int rowk = mb * 16 + lo;
      int c0 = hi ^ (rowk & 7);
      int c1 = (hi + 4) ^ (rowk & 7);
      bf16x8 bk0 = *(const bf16x8*)&Kc[rowk * 64 + c0 * 8];
      bf16x8 bk1 = *(const bf16x8*)&Kc[rowk * 64 + c1 * 8];
#pragma unroll
      for (int f = 0; f < 2; f++) {
        f32x4 dacc = zz;
        dacc = MFMA(aq[f][0], bk0, dacc);
        dacc = MFMA(aq[f][1], bk1, dacc);
#pragma unroll
        for (int rg = 0; rg < 4; rg++) {
          float pv = dacc[rg] * (aqn[f][rg] * ik[mb] + beta);
          int prow = w * 32 + f * 16 + hi * 4 + rg;
          int chunk = (mb * 2 + (lo >> 3)) ^ (prow & 7);
          Pl[prow * 72 + chunk * 8 + (l & 7)] = f2bf_hw(pv);
        }
      }
    }
  };
  auto PV = [&](const u16* Vc) {
#pragma unroll
    for (int c = 0; c < 2; c++) {
      bf16x8 ap[2];
#pragma unroll
      for (int f = 0; f < 2; f++) {
        int prow = w * 32 + f * 16 + lo;
        int chunk = (hi + 4 * c) ^ (prow & 7);
        ap[f] = *(const bf16x8*)&Pl[prow * 72 + chunk * 8];
      }
#pragma unroll
      for (int db = 0; db < 4; db++) {
        int rowd = db * 16 + lo;
        int ck = (hi + 4 * c) ^ (rowd & 7);
        bf16x8 bv = *(const bf16x8*)&Vc[rowd * 64 + ck * 8];
#pragma unroll
        for (int f = 0; f < 2; f++)
          oacc[f][db] = MFMA(ap[f], bv, oacc[f][db]);
      }
    }
  };

  int t0 = s * 16;

  STAGE(t0, 0);
  LOADIK(ikA, t0);
  __syncthreads();   // implicit vmcnt(0): tile t0 resident

  for (int t = t0; t < t0 + 16; t += 2) {
    STAGE(t + 1, 1);
    LOADIK(ikB, t + 1);
    QKP(Kl[0], ikA);
    PV(Vl[0]);
    __syncthreads();

    if (t + 2 < t0 + 16) {
      STAGE(t + 2, 0);
      LOADIK(ikA, t + 2);
    }
    QKP(Kl[1], ikB);
    PV(Vl[1]);
    __syncthreads();
  }

  // epilogue: f32 partial store
  float* op = opart + ((size_t)(s * 256 + qg128)) * 8192;
#pragma unroll
  for (int f = 0; f < 2; f++)
#pragma unroll
    for (int db = 0; db < 4; db++) {
      int dcol = db * 16 + lo;
#pragma unroll
      for (int rg = 0; rg < 4; rg++) {
        int r = w * 32 + f * 16 + hi * 4 + rg;
        op[r * 64 + dcol] = oacc[f][db][rg];
      }
    }
}

// ---------------------------------------------------------------------------
// K3b: reduce the two m-split partials + rank-1 correction -> A2 bf16
// grid 512 (qglob64), 256 threads
// ---------------------------------------------------------------------------
__global__ __launch_bounds__(256) void reduce_o(const float* __restrict__ opart,
                                                const float* __restrict__ mq,
                                                const float* __restrict__ hp,
                                                const float* __restrict__ rv,
                                                u16* __restrict__ A2) {
  int qglob = blockIdx.x;                  // 0..511 (64-row granularity)
  int qt64 = qglob & 31, b = (qglob >> 5) & 1, h = qglob >> 6;
  int tid = threadIdx.x;
  int r = tid >> 2;              // 0..63
  int c0 = (tid & 3) * 16;       // 0,16,32,48
  int n = qt64 * 64 + r;
  int qg128 = (h * 2 + b) * 16 + (qt64 >> 1);
  int rowin = (qt64 & 1) * 64 + r;
  float gamma = hp[h * 4 + 2];
  float mqg = gamma * mq[((size_t)h * 2 + b) * CN + n];
  const float* p0 = opart + (size_t)qg128 * 8192 + rowin * 64 + c0;
  const float* p1 = opart + ((size_t)(256 + qg128)) * 8192 + rowin * 64 + c0;
  const float* rh = rv + ((size_t)h * 2 + b) * 64 + c0;
  u16* dst = A2 + ((size_t)(b * CN + n)) * CD + h * 64 + c0;
#pragma unroll
  for (int jc = 0; jc < 4; jc++) {
    f32x4 a = *(const f32x4*)&p0[jc * 4];
    f32x4 bq = *(const f32x4*)&p1[jc * 4];
    f32x4 rr = *(const f32x4*)&rh[jc * 4];
#pragma unroll
    for (int e = 0; e < 4; e++)
      dst[jc * 4 + e] = f2bf(a[e] + bq[e] - mqg * rr[e]);
  }
}

// ---------------------------------------------------------------------------
extern "C" void kernel_launch(void* const* d_in, const int* in_sizes, int n_in,
                              void* d_out, int out_size, void* d_ws, size_t ws_size,
                              hipStream_t stream) {
  const float* q = (const float*)d_in[0];
  const float* k = (const float*)d_in[1];
  const float* v = (const float*)d_in[2];
  const float* ln_g = (const float*)d_in[3];
  const float* ln_b = (const float*)d_in[4];
  const float* W_in = (const float*)d_in[5];
  const float* wp_w1 = (const float*)d_in[6];
  const float* wp_b1 = (const float*)d_in[7];
  const float* wp_lng = (const float*)d_in[8];
  const float* wp_lnb = (const float*)d_in[9];
  const float* wp_w2 = (const float*)d_in[10];
  const float* wp_b2 = (const float*)d_in[11];
  const float* W_out = (const float*)d_in[12];
  const float* b_out = (const float*)d_in[13];

  char* ws = (char*)d_ws;
  u16* xln = (u16*)(ws + 0);              // 12,582,912 B
  u16* F = (u16*)(ws + 12582912);         // 12,582,912 B  [3][B][N][512]
  u16* Wi = (u16*)(ws + 25165824);        // 524,288 B
  u16* Wo = (u16*)(ws + 25690112);        // 524,288 B
  u16* fvT = (u16*)(ws + 26214400);       // 4,194,304 B   [H][B][64][2048]
  u16* A2 = (u16*)(ws + 30408704);        // 4,194,304 B   [B][N][512]
  float* iqn = (float*)(ws + 34603008);   // 131,072 B each
  float* mq = (float*)(ws + 34734080);
  float* ikn = (float*)(ws + 34865152);
  float* mk = (float*)(ws + 34996224);
  float* qgp = (float*)(ws + 35127296);   // 65,536 B
  float* kgp = (float*)(ws + 35192832);   // 65,536 B
  float* hp = (float*)(ws + 35258368);    // 128 B
  float* rv = (float*)(ws + 35258496);    // 4,096 B
  float* rpart = (float*)(ws + 35262592); // 131,072 B
  float* opart = (float*)(ws + 35393664); // 16,777,216 B  [2][256][128][64] f32

  u16* F0 = F;
  u16* F1 = F + 2097152;
  u16* F2 = F + 4194304;

  ln_kernel<<<12288, 256, 0, stream>>>(q, k, v, ln_g, ln_b, xln);
  convw_kernel<<<1024, 256, 0, stream>>>(W_in, W_out, Wi, Wo);
  gemm_bt<1, 0><<<dim3(96, 4), 256, 0, stream>>>(xln, Wi, (void*)F, nullptr);
  statsum_kernel<<<256, 256, 0, stream>>>(F0, F1, iqn, mq, ikn, mk, qgp, kgp);
  transpose_v<<<512, 256, 0, stream>>>(F2, mk, fvT, rpart);
  finalize_mlp_kernel<<<1, 1024, 0, stream>>>(rpart, qgp, kgp, wp_w1, wp_b1,
                                              wp_lng, wp_lnb, wp_w2, wp_b2, rv, hp);
  attn_kernel<<<512, 256, 0, stream>>>(F0, F1, fvT, iqn, ikn, hp, opart);
  reduce_o<<<512, 256, 0, stream>>>(opart, mq, hp, rv, A2);
  gemm_bt<0, 1><<<dim3(32, 4), 256, 0, stream>>>(A2, Wo, d_out, b_out);
}

// Round 9
// 81.571 us; speedup vs baseline: 1.2849x; 1.1644x over previous
//
#include <hip/hip_runtime.h>
#include <stdint.h>

// Problem constants
#define CH 8      // heads
#define CDH 64    // dim head
#define CB 2      // batch
#define CN 2048   // seq
#define CD 512    // model dim

typedef float f32x4 __attribute__((ext_vector_type(4)));
typedef __bf16 bf16x8 __attribute__((ext_vector_type(8)));
typedef unsigned short u16;

#define MFMA(a, b, c) __builtin_amdgcn_mfma_f32_16x16x32_bf16((a), (b), (c), 0, 0, 0)
#define GLOAD16(g, l)                                                              \
  __builtin_amdgcn_global_load_lds((const __attribute__((address_space(1))) void*)(g), \
                                   (__attribute__((address_space(3))) void*)(l), 16, 0, 0)

__device__ __forceinline__ u16 f2bf(float f) {
  union { float f; unsigned u; } c; c.f = f;
  return (u16)((c.u + 0x7FFFu + ((c.u >> 16) & 1u)) >> 16);
}
__device__ __forceinline__ float bf2f(u16 h) {
  union { unsigned u; float f; } c; c.u = ((unsigned)h) << 16;
  return c.f;
}

// ---------------------------------------------------------------------------
// K0: LayerNorm over D=512 for q,k,v -> xln bf16 [3*4096][512]
// ---------------------------------------------------------------------------
__global__ __launch_bounds__(256) void ln_kernel(const float* __restrict__ q,
                                                 const float* __restrict__ k,
                                                 const float* __restrict__ v,
                                                 const float* __restrict__ g,
                                                 const float* __restrict__ bb,
                                                 u16* __restrict__ xln) {
  int row = blockIdx.x;                 // 0..12287
  int t = row >> 12;                    // /4096
  int rr = row & 4095;
  const float* src = (t == 0 ? q : (t == 1 ? k : v)) + (size_t)rr * CD;
  int tid = threadIdx.x;
  float x0 = src[tid], x1 = src[tid + 256];
  float s = x0 + x1, s2 = x0 * x0 + x1 * x1;
#pragma unroll
  for (int m = 1; m < 64; m <<= 1) { s += __shfl_xor(s, m); s2 += __shfl_xor(s2, m); }
  __shared__ float red[8];
  int w = tid >> 6;
  if ((tid & 63) == 0) { red[w] = s; red[4 + w] = s2; }
  __syncthreads();
  s = red[0] + red[1] + red[2] + red[3];
  s2 = red[4] + red[5] + red[6] + red[7];
  float mean = s * (1.f / 512.f);
  float var = s2 * (1.f / 512.f) - mean * mean;
  float rstd = rsqrtf(var + 1e-5f);
  u16* dst = xln + (size_t)row * CD;
  dst[tid]       = f2bf((x0 - mean) * rstd * g[tid] + bb[tid]);
  dst[tid + 256] = f2bf((x1 - mean) * rstd * g[tid + 256] + bb[tid + 256]);
}

// ---------------------------------------------------------------------------
// K0w: convert W_in, W_out to bf16
// ---------------------------------------------------------------------------
__global__ __launch_bounds__(256) void convw_kernel(const float* __restrict__ wi_f,
                                                    const float* __restrict__ wo_f,
                                                    u16* __restrict__ wi,
                                                    u16* __restrict__ wo) {
  int i = blockIdx.x * 256 + threadIdx.x;   // < 262144
  wi[i] = f2bf(wi_f[i]);
  wo[i] = f2bf(wo_f[i]);
}

// ---------------------------------------------------------------------------
// Generic C = A * Bt^T bf16 MFMA GEMM, K=512, BM=BN=128, BK=64, double-buffered
// ---------------------------------------------------------------------------
template <int OUT_BF16, int ADD_BIAS>
__global__ __launch_bounds__(256) void gemm_bt(const u16* __restrict__ A,
                                               const u16* __restrict__ Bt,
                                               void* __restrict__ Cout,
                                               const float* __restrict__ bias) {
  __shared__ u16 Al[2][128 * 64];
  __shared__ u16 Bl[2][128 * 64];
  int tm = blockIdx.x * 128, tn = blockIdx.y * 128;
  int tid = threadIdx.x;
  int w = tid >> 6, l = tid & 63;
  int wr = w >> 1, wc = w & 1;

  f32x4 zz = {0.f, 0.f, 0.f, 0.f};
  f32x4 acc[4][4];
#pragma unroll
  for (int mi = 0; mi < 4; mi++)
#pragma unroll
    for (int ni = 0; ni < 4; ni++) acc[mi][ni] = zz;

  int rowA = 8 * w + (l >> 3);
  int sl = l & 7;

#pragma unroll
  for (int i = 0; i < 4; i++) {
    int rl = rowA + 32 * i;
    int sp = sl ^ (rl & 7);
    GLOAD16(A + (size_t)(tm + rl) * CD + sp * 8, (char*)Al[0] + w * 1024 + i * 4096);
    GLOAD16(Bt + (size_t)(tn + rl) * CD + sp * 8, (char*)Bl[0] + w * 1024 + i * 4096);
  }
  __syncthreads();

  int cur = 0;
  for (int kt = 0; kt < 8; ++kt) {
    if (kt + 1 < 8) {
      int nxt = cur ^ 1;
#pragma unroll
      for (int i = 0; i < 4; i++) {
        int rl = rowA + 32 * i;
        int sp = sl ^ (rl & 7);
        GLOAD16(A + (size_t)(tm + rl) * CD + (kt + 1) * 64 + sp * 8,
                (char*)Al[nxt] + w * 1024 + i * 4096);
        GLOAD16(Bt + (size_t)(tn + rl) * CD + (kt + 1) * 64 + sp * 8,
                (char*)Bl[nxt] + w * 1024 + i * 4096);
      }
    }
    const u16* Ac = Al[cur];
    const u16* Bc = Bl[cur];
#pragma unroll
    for (int kk = 0; kk < 2; kk++) {
      bf16x8 af[4], bfr[4];
#pragma unroll
      for (int mi = 0; mi < 4; mi++) {
        int row = wr * 64 + mi * 16 + (l & 15);
        int slot = ((l >> 4) + 4 * kk) ^ (row & 7);
        af[mi] = *(const bf16x8*)&Ac[row * 64 + slot * 8];
      }
#pragma unroll
      for (int ni = 0; ni < 4; ni++) {
        int row = wc * 64 + ni * 16 + (l & 15);
        int slot = ((l >> 4) + 4 * kk) ^ (row & 7);
        bfr[ni] = *(const bf16x8*)&Bc[row * 64 + slot * 8];
      }
#pragma unroll
      for (int mi = 0; mi < 4; mi++)
#pragma unroll
        for (int ni = 0; ni < 4; ni++)
          acc[mi][ni] = MFMA(af[mi], bfr[ni], acc[mi][ni]);
    }
    if (kt + 1 < 8) {
      __syncthreads();
      cur ^= 1;
    }
  }
#pragma unroll
  for (int mi = 0; mi < 4; mi++)
#pragma unroll
    for (int ni = 0; ni < 4; ni++) {
      int col = tn + wc * 64 + ni * 16 + (l & 15);
      float bv = ADD_BIAS ? bias[col] : 0.f;
#pragma unroll
      for (int rg = 0; rg < 4; rg++) {
        int rowg = tm + wr * 64 + mi * 16 + (l >> 4) * 4 + rg;
        float vout = acc[mi][ni][rg] + bv;
        if (OUT_BF16)
          ((u16*)Cout)[(size_t)rowg * CD + col] = f2bf(vout);
        else
          ((float*)Cout)[(size_t)rowg * CD + col] = vout;
      }
    }
}

// ---------------------------------------------------------------------------
// K1c: merged stats + global partial sums (single pass over F0,F1).
// grid 256 (h:3 low | ch:5), 256 threads.
// ---------------------------------------------------------------------------
__global__ __launch_bounds__(256) void statsum_kernel(const u16* __restrict__ F0,
                                                      const u16* __restrict__ F1,
                                                      float* __restrict__ iqn,
                                                      float* __restrict__ ikn,
                                                      float* __restrict__ qgp,
                                                      float* __restrict__ kgp) {
  int h = blockIdx.x & 7, ch = blockIdx.x >> 3;   // ch in [0,32)
  int tid = threadIdx.x;
  int r0 = tid >> 3;          // 0..31
  int dcx = tid & 7;
  int dc = dcx * 8;
  float aq[8], ak[8];
#pragma unroll
  for (int j = 0; j < 8; j++) { aq[j] = 0.f; ak[j] = 0.f; }
#pragma unroll
  for (int i = 0; i < 4; i++) {
    int row = ch * 128 + i * 32 + r0;   // global row in [0,4096)
    bf16x8 vq = *(const bf16x8*)&F0[(size_t)row * CD + h * 64 + dc];
    bf16x8 vk = *(const bf16x8*)&F1[(size_t)row * CD + h * 64 + dc];
    float s2q = 0.f, s2k = 0.f;
#pragma unroll
    for (int j = 0; j < 8; j++) {
      float fq = (float)vq[j], fk = (float)vk[j];
      aq[j] += fq; ak[j] += fk;
      s2q += fq * fq;
      s2k += fk * fk;
    }
#pragma unroll
    for (int m = 1; m < 8; m <<= 1) {
      s2q += __shfl_xor(s2q, m);
      s2k += __shfl_xor(s2k, m);
    }
    if (dcx == 0) {
      int b = row >> 11, n = row & 2047;
      size_t o = ((size_t)h * 2 + b) * CN + n;
      iqn[o] = 1.f / sqrtf(s2q);
      ikn[o] = 1.f / sqrtf(s2k);
    }
  }
  __shared__ float red[2][32][64];
#pragma unroll
  for (int j = 0; j < 8; j++) { red[0][r0][dc + j] = aq[j]; red[1][r0][dc + j] = ak[j]; }
  __syncthreads();
  if (tid < 64) {
    float sq = 0.f, sk = 0.f;
#pragma unroll
    for (int rr = 0; rr < 32; rr++) { sq += red[0][rr][tid]; sk += red[1][rr][tid]; }
    qgp[(ch * 8 + h) * 64 + tid] = sq;
    kgp[(ch * 8 + h) * 64 + tid] = sk;
  }
}

// ---------------------------------------------------------------------------
// K1b: transpose fk and fv per (h,b): -> fkT, fvT, fvhT(=fv*ikn) [hb][64][2048]
// grid 512 (h:3|b:1|ntile:5), 256 threads
// ---------------------------------------------------------------------------
__global__ __launch_bounds__(256) void transpose_kv(const u16* __restrict__ F1,
                                                    const u16* __restrict__ F2,
                                                    const float* __restrict__ ikn,
                                                    u16* __restrict__ fkT,
                                                    u16* __restrict__ fvT,
                                                    u16* __restrict__ fvhT) {
  int bid = blockIdx.x;
  int nt = bid & 31, b = (bid >> 5) & 1, h = bid >> 6;
  int hb = h * 2 + b;
  __shared__ u16 Tk[64 * 72];
  __shared__ u16 Tv[64 * 72];
  int tid = threadIdx.x;
  int n = tid >> 2;
#pragma unroll
  for (int p = 0; p < 2; p++) {
    int c = (tid & 3) + 4 * p;
    size_t src = ((size_t)(b * CN + nt * 64 + n) * CD) + h * 64 + c * 8;
    *(bf16x8*)&Tk[n * 72 + c * 8] = *(const bf16x8*)&F1[src];
    *(bf16x8*)&Tv[n * 72 + c * 8] = *(const bf16x8*)&F2[src];
  }
  __syncthreads();
  int d = tid >> 2;
  const float* ikn_hb = ikn + (size_t)hb * CN + nt * 64;
#pragma unroll
  for (int p = 0; p < 2; p++) {
    int c = (tid & 3) + 4 * p;   // n-chunk
    u16 tk[8], tv[8], th[8];
#pragma unroll
    for (int j = 0; j < 8; j++) {
      tk[j] = Tk[(c * 8 + j) * 72 + d];
      tv[j] = Tv[(c * 8 + j) * 72 + d];
      th[j] = f2bf(bf2f(tv[j]) * ikn_hb[c * 8 + j]);
    }
    size_t dst = (((size_t)hb * 64 + d) * CN) + nt * 64 + c * 8;
    *(bf16x8*)&fkT[dst] = *(bf16x8*)tk;
    *(bf16x8*)&fvT[dst] = *(bf16x8*)tv;
    *(bf16x8*)&fvhT[dst] = *(bf16x8*)th;
  }
}

// ---------------------------------------------------------------------------
// K2b: reduce qgp/kgp + per-head blend MLP -> hp[h] = {1-w, w/64, w}
// 1 block x 512 threads
// ---------------------------------------------------------------------------
__global__ __launch_bounds__(512) void mlp_kernel(const float* __restrict__ qgp,
                                                  const float* __restrict__ kgp,
                                                  const float* __restrict__ w1,
                                                  const float* __restrict__ b1,
                                                  const float* __restrict__ lng,
                                                  const float* __restrict__ lnb,
                                                  const float* __restrict__ w2,
                                                  const float* __restrict__ b2,
                                                  float* __restrict__ hp) {
  int o = threadIdx.x;   // < 512
  __shared__ float qg[512], kg[512];
  {
    int h = o >> 6, dd = o & 63;
    float s1 = 0.f, s2 = 0.f;
#pragma unroll
    for (int c = 0; c < 32; c++) {
      s1 += qgp[(c * 8 + h) * 64 + dd];
      s2 += kgp[(c * 8 + h) * 64 + dd];
    }
    qg[o] = s1 * (1.f / 4096.f);
    kg[o] = s2 * (1.f / 4096.f);
  }
  __syncthreads();
  {
    int h = o >> 6, oo = o & 63;
    float acc = b1[oo];
#pragma unroll 8
    for (int i = 0; i < 64; i++)
      acc += qg[h * 64 + i] * w1[oo * 128 + i] + kg[h * 64 + i] * w1[oo * 128 + 64 + i];
    float s1 = acc, s2 = acc * acc;
#pragma unroll
    for (int m = 1; m < 64; m <<= 1) { s1 += __shfl_xor(s1, m); s2 += __shfl_xor(s2, m); }
    float mean = s1 * (1.f / 64.f);
    float var = s2 * (1.f / 64.f) - mean * mean;
    float y = (acc - mean) * rsqrtf(var + 1e-5f) * lng[oo] + lnb[oo];
    float hid = fmaxf(y, 0.f);
    float t = hid * w2[oo];
#pragma unroll
    for (int m = 1; m < 64; m <<= 1) t += __shfl_xor(t, m);
    float wv = 1.f / (1.f + expf(-(t + b2[0])));
    if (oo == 0) {
      hp[h * 4 + 0] = 1.f - wv;
      hp[h * 4 + 1] = wv * (1.f / 64.f);
      hp[h * 4 + 2] = wv;
    }
  }
}

// ---------------------------------------------------------------------------
// K3a: gemm_M — per (h,b): M1 = K^T V_hat, M2 = K^T V (each 64x64), m-split 16.
// grid 256 (hb:4 low | ms:4), 256 threads. Mpart[(hb*16+ms)][j=mat*64+i][d] f32.
// ---------------------------------------------------------------------------
__global__ __launch_bounds__(256) void gemm_M(const u16* __restrict__ fkT,
                                              const u16* __restrict__ fvT,
                                              const u16* __restrict__ fvhT,
                                              float* __restrict__ Mpart) {
  int bid = blockIdx.x;
  int hb = bid & 15, ms = bid >> 4;
  int tid = threadIdx.x, w = tid >> 6, l = tid & 63;
  int lo = l & 15, hi = l >> 4;

  __shared__ u16 Ak[64 * 64];
  __shared__ u16 Bv[64 * 64];
  __shared__ u16 Bh[64 * 64];

  const u16* Ab = fkT + (size_t)hb * 64 * CN;
  const u16* Vb = fvT + (size_t)hb * 64 * CN;
  const u16* Hb = fvhT + (size_t)hb * 64 * CN;

  f32x4 zz = {0.f, 0.f, 0.f, 0.f};
  f32x4 acc[2][4];
#pragma unroll
  for (int mat = 0; mat < 2; mat++)
#pragma unroll
    for (int dt = 0; dt < 4; dt++) acc[mat][dt] = zz;

  int rls = 8 * w + (l >> 3);
  int sls = l & 7;

  for (int kt = 0; kt < 2; ++kt) {
    int mc = ms * 128 + kt * 64;
#pragma unroll
    for (int i = 0; i < 2; i++) {
      int row = rls + 32 * i;
      int sp = sls ^ (row & 7);
      GLOAD16(Ab + (size_t)row * CN + mc + sp * 8, (char*)Ak + w * 1024 + i * 4096);
      GLOAD16(Vb + (size_t)row * CN + mc + sp * 8, (char*)Bv + w * 1024 + i * 4096);
      GLOAD16(Hb + (size_t)row * CN + mc + sp * 8, (char*)Bh + w * 1024 + i * 4096);
    }
    __syncthreads();
#pragma unroll
    for (int kk = 0; kk < 2; kk++) {
      int arow = w * 16 + lo;
      int aslot = (hi + 4 * kk) ^ (arow & 7);
      bf16x8 af = *(const bf16x8*)&Ak[arow * 64 + aslot * 8];
#pragma unroll
      for (int dt = 0; dt < 4; dt++) {
        int brow = dt * 16 + lo;
        int bslot = (hi + 4 * kk) ^ (brow & 7);
        bf16x8 bh = *(const bf16x8*)&Bh[brow * 64 + bslot * 8];
        bf16x8 bv = *(const bf16x8*)&Bv[brow * 64 + bslot * 8];
        acc[0][dt] = MFMA(af, bh, acc[0][dt]);   // M1 (scaled V)
        acc[1][dt] = MFMA(af, bv, acc[1][dt]);   // M2
      }
    }
    __syncthreads();
  }

  float* outp = Mpart + ((size_t)(hb * 16 + ms)) * 8192;
#pragma unroll
  for (int mat = 0; mat < 2; mat++)
#pragma unroll
    for (int dt = 0; dt < 4; dt++) {
      int d = dt * 16 + lo;
#pragma unroll
      for (int rg = 0; rg < 4; rg++) {
        int j = mat * 64 + w * 16 + hi * 4 + rg;
        outp[j * 64 + d] = acc[mat][dt][rg];
      }
    }
}

// ---------------------------------------------------------------------------
// K3b: reduceM — sum 16 m-split partials, apply alpha/beta + rank-1 fold,
// write Bmat[hb][jrow][icol] bf16: jrow<64: alpha*M1[i=icol][d=jrow];
// jrow=64+d: beta*M2[icol][d] - (gamma/4096)*S2[d].  grid 16, 256 thr.
// ---------------------------------------------------------------------------
__global__ __launch_bounds__(256) void reduceM(const float* __restrict__ Mpart,
                                               const float* __restrict__ hp,
                                               u16* __restrict__ Bmat) {
  int hb = blockIdx.x;
  int h = hb >> 1;
  float alpha = hp[h * 4 + 0], beta = hp[h * 4 + 1], gamma = hp[h * 4 + 2];
  __shared__ float Ms[128 * 65];
  __shared__ float S2[64];
  int tid = threadIdx.x;
#pragma unroll
  for (int e = 0; e < 32; e++) {
    int idx = e * 256 + tid;
    int j = idx >> 6, d = idx & 63;
    float s = 0.f;
#pragma unroll
    for (int ms = 0; ms < 16; ms++)
      s += Mpart[((size_t)(hb * 16 + ms)) * 8192 + idx];
    Ms[j * 65 + d] = s;
  }
  __syncthreads();
  if (tid < 64) {
    float s = 0.f;
#pragma unroll
    for (int i = 0; i < 64; i++) s += Ms[(64 + i) * 65 + tid];
    S2[tid] = s;
  }
  __syncthreads();
#pragma unroll
  for (int e = 0; e < 32; e++) {
    int idx = e * 256 + tid;
    int jr = idx >> 6, ic = idx & 63;
    float v;
    if (jr < 64) v = alpha * Ms[ic * 65 + jr];
    else {
      int d = jr - 64;
      v = beta * Ms[(64 + ic) * 65 + d] - (gamma * (1.f / 4096.f)) * S2[d];
    }
    Bmat[(size_t)hb * 8192 + idx] = f2bf(v);
  }
}

// ---------------------------------------------------------------------------
// K3c: gemm_out — out[n] = iqn[n]*(fq@aM1) + fq@(bM2 - rank1)  -> A2 bf16.
// grid 256 (hb*16+qt), 256 threads (4 waves), no LDS, no barriers.
// Wave w: rows w*32..w*32+31 (2 frags), all 8 j-tiles; K=64 (2 kk).
// ---------------------------------------------------------------------------
__global__ __launch_bounds__(256) void gemm_out(const u16* __restrict__ F0,
                                                const u16* __restrict__ Bmat,
                                                const float* __restrict__ iqn,
                                                u16* __restrict__ A2) {
  int bid = blockIdx.x;
  int hb = bid >> 4, qt = bid & 15;
  int b = hb & 1, h = hb >> 1;
  int tid = threadIdx.x, w = tid >> 6, l = tid & 63;
  int lo = l & 15, hi = l >> 4;
  int qbase = qt * 128;

  const u16* Bm = Bmat + (size_t)hb * 8192;
  bf16x8 bm[8][2];
#pragma unroll
  for (int jt = 0; jt < 8; jt++)
#pragma unroll
    for (int kk = 0; kk < 2; kk++)
      bm[jt][kk] = *(const bf16x8*)&Bm[(jt * 16 + lo) * 64 + hi * 8 + kk * 32];

  f32x4 zz = {0.f, 0.f, 0.f, 0.f};
  f32x4 acc[2][8];
#pragma unroll
  for (int f = 0; f < 2; f++)
#pragma unroll
    for (int jt = 0; jt < 8; jt++) acc[f][jt] = zz;

#pragma unroll
  for (int f = 0; f < 2; f++) {
    const u16* qp = F0 + ((size_t)(b * CN + qbase + w * 32 + f * 16 + lo)) * CD +
                    h * 64 + hi * 8;
    bf16x8 a0 = *(const bf16x8*)qp;
    bf16x8 a1 = *(const bf16x8*)(qp + 32);
#pragma unroll
    for (int jt = 0; jt < 8; jt++) {
      acc[f][jt] = MFMA(a0, bm[jt][0], acc[f][jt]);
      acc[f][jt] = MFMA(a1, bm[jt][1], acc[f][jt]);
    }
  }

  const float* iqn_hb = iqn + (size_t)hb * CN;
#pragma unroll
  for (int f = 0; f < 2; f++) {
    float iqv[4];
    int nb = qbase + w * 32 + f * 16 + hi * 4;
#pragma unroll
    for (int rg = 0; rg < 4; rg++) iqv[rg] = iqn_hb[nb + rg];
#pragma unroll
    for (int jt = 0; jt < 4; jt++) {
      int d = jt * 16 + lo;
#pragma unroll
      for (int rg = 0; rg < 4; rg++) {
        float vout = iqv[rg] * acc[f][jt][rg] + acc[f][jt + 4][rg];
        int n = nb + rg;
        A2[((size_t)(b * CN + n)) * CD + h * 64 + d] = f2bf(vout);
      }
    }
  }
}

// ---------------------------------------------------------------------------
extern "C" void kernel_launch(void* const* d_in, const int* in_sizes, int n_in,
                              void* d_out, int out_size, void* d_ws, size_t ws_size,
                              hipStream_t stream) {
  const float* q = (const float*)d_in[0];
  const float* k = (const float*)d_in[1];
  const float* v = (const float*)d_in[2];
  const float* ln_g = (const float*)d_in[3];
  const float* ln_b = (const float*)d_in[4];
  const float* W_in = (const float*)d_in[5];
  const float* wp_w1 = (const float*)d_in[6];
  const float* wp_b1 = (const float*)d_in[7];
  const float* wp_lng = (const float*)d_in[8];
  const float* wp_lnb = (const float*)d_in[9];
  const float* wp_w2 = (const float*)d_in[10];
  const float* wp_b2 = (const float*)d_in[11];
  const float* W_out = (const float*)d_in[12];
  const float* b_out = (const float*)d_in[13];

  char* ws = (char*)d_ws;
  u16* xln = (u16*)(ws + 0);              // 12,582,912 B
  u16* F = (u16*)(ws + 12582912);         // 12,582,912 B  [3][B][N][512]
  u16* Wi = (u16*)(ws + 25165824);        // 524,288 B
  u16* Wo = (u16*)(ws + 25690112);        // 524,288 B
  u16* fkT = (u16*)(ws + 26214400);       // 4,194,304 B   [HB][64][2048]
  u16* fvT = (u16*)(ws + 30408704);       // 4,194,304 B
  u16* fvhT = (u16*)(ws + 34603008);      // 4,194,304 B
  u16* A2 = (u16*)(ws + 38797312);        // 4,194,304 B   [B][N][512]
  float* iqn = (float*)(ws + 42991616);   // 131,072 B
  float* ikn = (float*)(ws + 43122688);   // 131,072 B
  float* qgp = (float*)(ws + 43253760);   // 65,536 B
  float* kgp = (float*)(ws + 43319296);   // 65,536 B
  float* hp = (float*)(ws + 43384832);    // 128 B
  float* Mpart = (float*)(ws + 43384960); // 8,388,608 B   [256][128][64] f32
  u16* Bmat = (u16*)(ws + 51773568);      // 262,144 B     [16][128][64] bf16

  u16* F0 = F;
  u16* F1 = F + 2097152;
  u16* F2 = F + 4194304;

  ln_kernel<<<12288, 256, 0, stream>>>(q, k, v, ln_g, ln_b, xln);
  convw_kernel<<<1024, 256, 0, stream>>>(W_in, W_out, Wi, Wo);
  gemm_bt<1, 0><<<dim3(96, 4), 256, 0, stream>>>(xln, Wi, (void*)F, nullptr);
  statsum_kernel<<<256, 256, 0, stream>>>(F0, F1, iqn, ikn, qgp, kgp);
  transpose_kv<<<512, 256, 0, stream>>>(F1, F2, ikn, fkT, fvT, fvhT);
  mlp_kernel<<<1, 512, 0, stream>>>(qgp, kgp, wp_w1, wp_b1, wp_lng, wp_lnb,
                                    wp_w2, wp_b2, hp);
  gemm_M<<<256, 256, 0, stream>>>(fkT, fvT, fvhT, Mpart);
  reduceM<<<16, 256, 0, stream>>>(Mpart, hp, Bmat);
  gemm_out<<<256, 256, 0, stream>>>(F0, Bmat, iqn, A2);
  gemm_bt<0, 1><<<dim3(32, 4), 256, 0, stream>>>(A2, Wo, d_out, b_out);
}

// Round 10
// 72.106 us; speedup vs baseline: 1.4536x; 1.1313x over previous
//
#include <hip/hip_runtime.h>
#include <stdint.h>

// Problem constants
#define CH 8      // heads
#define CDH 64    // dim head
#define CB 2      // batch
#define CN 2048   // seq
#define CD 512    // model dim

typedef float f32x4 __attribute__((ext_vector_type(4)));
typedef __bf16 bf16x8 __attribute__((ext_vector_type(8)));
typedef unsigned short u16;

#define MFMA(a, b, c) __builtin_amdgcn_mfma_f32_16x16x32_bf16((a), (b), (c), 0, 0, 0)
#define GLOAD16(g, l)                                                              \
  __builtin_amdgcn_global_load_lds((const __attribute__((address_space(1))) void*)(g), \
                                   (__attribute__((address_space(3))) void*)(l), 16, 0, 0)

__device__ __forceinline__ u16 f2bf(float f) {
  union { float f; unsigned u; } c; c.f = f;
  return (u16)((c.u + 0x7FFFu + ((c.u >> 16) & 1u)) >> 16);
}
__device__ __forceinline__ float bf2f(u16 h) {
  union { unsigned u; float f; } c; c.u = ((unsigned)h) << 16;
  return c.f;
}

// ---------------------------------------------------------------------------
// K0: LayerNorm for q,k,v -> xln bf16 [3*4096][512]; tail blocks convert W
// grid 13312 = 12288 LN + 1024 conv
// ---------------------------------------------------------------------------
__global__ __launch_bounds__(256) void ln_convw_kernel(const float* __restrict__ q,
                                                       const float* __restrict__ k,
                                                       const float* __restrict__ v,
                                                       const float* __restrict__ g,
                                                       const float* __restrict__ bb,
                                                       u16* __restrict__ xln,
                                                       const float* __restrict__ wi_f,
                                                       const float* __restrict__ wo_f,
                                                       u16* __restrict__ wi,
                                                       u16* __restrict__ wo) {
  int row = blockIdx.x;
  int tid = threadIdx.x;
  if (row >= 12288) {
    int i = (row - 12288) * 256 + tid;   // < 262144
    wi[i] = f2bf(wi_f[i]);
    wo[i] = f2bf(wo_f[i]);
    return;
  }
  int t = row >> 12;
  int rr = row & 4095;
  const float* src = (t == 0 ? q : (t == 1 ? k : v)) + (size_t)rr * CD;
  float x0 = src[tid], x1 = src[tid + 256];
  float s = x0 + x1, s2 = x0 * x0 + x1 * x1;
#pragma unroll
  for (int m = 1; m < 64; m <<= 1) { s += __shfl_xor(s, m); s2 += __shfl_xor(s2, m); }
  __shared__ float red[8];
  int w = tid >> 6;
  if ((tid & 63) == 0) { red[w] = s; red[4 + w] = s2; }
  __syncthreads();
  s = red[0] + red[1] + red[2] + red[3];
  s2 = red[4] + red[5] + red[6] + red[7];
  float mean = s * (1.f / 512.f);
  float var = s2 * (1.f / 512.f) - mean * mean;
  float rstd = rsqrtf(var + 1e-5f);
  u16* dst = xln + (size_t)row * CD;
  dst[tid]       = f2bf((x0 - mean) * rstd * g[tid] + bb[tid]);
  dst[tid + 256] = f2bf((x1 - mean) * rstd * g[tid + 256] + bb[tid + 256]);
}

// ---------------------------------------------------------------------------
// Generic C = A * Bt^T bf16 MFMA GEMM, K=512, BM=BN=128, BK=64, double-buffered.
// DO_STATS=1 (gemm1 only): epilogue computes per-row head-slice inv-norms
// (iqn for q rows, ikn for k rows) and per-block column sums (qgp/kgp).
// Wave (wr,wc): rows tm+wr*64+mi*16+hi*4+rg, cols tn+wc*64+ni*16+lo -> the
// wave's 64-col span is exactly head h = blockIdx.y*2+wc.
// ---------------------------------------------------------------------------
template <int OUT_BF16, int ADD_BIAS, int DO_STATS>
__global__ __launch_bounds__(256) void gemm_bt(const u16* __restrict__ A,
                                               const u16* __restrict__ Bt,
                                               void* __restrict__ Cout,
                                               const float* __restrict__ bias,
                                               float* __restrict__ iqn,
                                               float* __restrict__ ikn,
                                               float* __restrict__ qgp,
                                               float* __restrict__ kgp) {
  __shared__ u16 Al[2][128 * 64];
  __shared__ u16 Bl[2][128 * 64];
  int tm = blockIdx.x * 128, tn = blockIdx.y * 128;
  int tid = threadIdx.x;
  int w = tid >> 6, l = tid & 63;
  int wr = w >> 1, wc = w & 1;
  int lo = l & 15, hi = l >> 4;

  f32x4 zz = {0.f, 0.f, 0.f, 0.f};
  f32x4 acc[4][4];
#pragma unroll
  for (int mi = 0; mi < 4; mi++)
#pragma unroll
    for (int ni = 0; ni < 4; ni++) acc[mi][ni] = zz;

  int rowA = 8 * w + (l >> 3);
  int sl = l & 7;

#pragma unroll
  for (int i = 0; i < 4; i++) {
    int rl = rowA + 32 * i;
    int sp = sl ^ (rl & 7);
    GLOAD16(A + (size_t)(tm + rl) * CD + sp * 8, (char*)Al[0] + w * 1024 + i * 4096);
    GLOAD16(Bt + (size_t)(tn + rl) * CD + sp * 8, (char*)Bl[0] + w * 1024 + i * 4096);
  }
  __syncthreads();

  int cur = 0;
  for (int kt = 0; kt < 8; ++kt) {
    if (kt + 1 < 8) {
      int nxt = cur ^ 1;
#pragma unroll
      for (int i = 0; i < 4; i++) {
        int rl = rowA + 32 * i;
        int sp = sl ^ (rl & 7);
        GLOAD16(A + (size_t)(tm + rl) * CD + (kt + 1) * 64 + sp * 8,
                (char*)Al[nxt] + w * 1024 + i * 4096);
        GLOAD16(Bt + (size_t)(tn + rl) * CD + (kt + 1) * 64 + sp * 8,
                (char*)Bl[nxt] + w * 1024 + i * 4096);
      }
    }
    const u16* Ac = Al[cur];
    const u16* Bc = Bl[cur];
#pragma unroll
    for (int kk = 0; kk < 2; kk++) {
      bf16x8 af[4], bfr[4];
#pragma unroll
      for (int mi = 0; mi < 4; mi++) {
        int row = wr * 64 + mi * 16 + lo;
        int slot = (hi + 4 * kk) ^ (row & 7);
        af[mi] = *(const bf16x8*)&Ac[row * 64 + slot * 8];
      }
#pragma unroll
      for (int ni = 0; ni < 4; ni++) {
        int row = wc * 64 + ni * 16 + lo;
        int slot = (hi + 4 * kk) ^ (row & 7);
        bfr[ni] = *(const bf16x8*)&Bc[row * 64 + slot * 8];
      }
#pragma unroll
      for (int mi = 0; mi < 4; mi++)
#pragma unroll
        for (int ni = 0; ni < 4; ni++)
          acc[mi][ni] = MFMA(af[mi], bfr[ni], acc[mi][ni]);
    }
    if (kt + 1 < 8) {
      __syncthreads();
      cur ^= 1;
    }
  }

  if (DO_STATS) {
    int tblk = blockIdx.x;              // 0..31 q, 32..63 k, 64..95 v
    bool isq = tblk < 32, isk = (tblk >= 32) && (tblk < 64);
    if (isq || isk) {
      int h = blockIdx.y * 2 + wc;
      // per-row inv-norm of the 64-col head slice
#pragma unroll
      for (int mi = 0; mi < 4; mi++)
#pragma unroll
        for (int rg = 0; rg < 4; rg++) {
          float s2 = 0.f;
#pragma unroll
          for (int ni = 0; ni < 4; ni++) {
            float vv = acc[mi][ni][rg];
            s2 += vv * vv;
          }
#pragma unroll
          for (int m = 1; m < 16; m <<= 1) s2 += __shfl_xor(s2, m);
          if (lo == 0) {
            int rowg = tm + wr * 64 + mi * 16 + hi * 4 + rg;
            int rloc = rowg & 4095;
            int b = rloc >> 11, n = rloc & 2047;
            size_t o = ((size_t)h * 2 + b) * CN + n;
            float inv = rsqrtf(s2);
            if (isq) iqn[o] = inv; else ikn[o] = inv;
          }
        }
      // per-block column sums (128 rows)
      float cs[4];
#pragma unroll
      for (int ni = 0; ni < 4; ni++) {
        float s = 0.f;
#pragma unroll
        for (int mi = 0; mi < 4; mi++)
#pragma unroll
          for (int rg = 0; rg < 4; rg++) s += acc[mi][ni][rg];
        s += __shfl_xor(s, 16);
        s += __shfl_xor(s, 32);
        cs[ni] = s;
      }
      __syncthreads();                       // all waves done reading Al/Bl
      float* redl = (float*)&Al[0][0];       // [wr][wc][ni][lo] = 2*2*4*16
      if (hi == 0)
#pragma unroll
        for (int ni = 0; ni < 4; ni++) redl[((wr * 2 + wc) * 4 + ni) * 16 + lo] = cs[ni];
      __syncthreads();
      if (wr == 0 && hi == 0) {
#pragma unroll
        for (int ni = 0; ni < 4; ni++) {
          float vsum = redl[((0 * 2 + wc) * 4 + ni) * 16 + lo] +
                       redl[((1 * 2 + wc) * 4 + ni) * 16 + lo];
          int col = ni * 16 + lo;
          float* dstp = isq ? qgp : kgp;
          dstp[((tblk & 31) * 8 + h) * 64 + col] = vsum;
        }
      }
    }
  }

#pragma unroll
  for (int mi = 0; mi < 4; mi++)
#pragma unroll
    for (int ni = 0; ni < 4; ni++) {
      int col = tn + wc * 64 + ni * 16 + lo;
      float bv = ADD_BIAS ? bias[col] : 0.f;
#pragma unroll
      for (int rg = 0; rg < 4; rg++) {
        int rowg = tm + wr * 64 + mi * 16 + hi * 4 + rg;
        float vout = acc[mi][ni][rg] + bv;
        if (OUT_BF16)
          ((u16*)Cout)[(size_t)rowg * CD + col] = f2bf(vout);
        else
          ((float*)Cout)[(size_t)rowg * CD + col] = vout;
      }
    }
}

// ---------------------------------------------------------------------------
// K1b: transpose fk and fv per (h,b): -> fkT, fvT, fvhT(=fv*ikn) [hb][64][2048]
// grid 512 (h:3|b:1|ntile:5), 256 threads
// ---------------------------------------------------------------------------
__global__ __launch_bounds__(256) void transpose_kv(const u16* __restrict__ F1,
                                                    const u16* __restrict__ F2,
                                                    const float* __restrict__ ikn,
                                                    u16* __restrict__ fkT,
                                                    u16* __restrict__ fvT,
                                                    u16* __restrict__ fvhT) {
  int bid = blockIdx.x;
  int nt = bid & 31, b = (bid >> 5) & 1, h = bid >> 6;
  int hb = h * 2 + b;
  __shared__ u16 Tk[64 * 72];
  __shared__ u16 Tv[64 * 72];
  int tid = threadIdx.x;
  int n = tid >> 2;
#pragma unroll
  for (int p = 0; p < 2; p++) {
    int c = (tid & 3) + 4 * p;
    size_t src = ((size_t)(b * CN + nt * 64 + n) * CD) + h * 64 + c * 8;
    *(bf16x8*)&Tk[n * 72 + c * 8] = *(const bf16x8*)&F1[src];
    *(bf16x8*)&Tv[n * 72 + c * 8] = *(const bf16x8*)&F2[src];
  }
  __syncthreads();
  int d = tid >> 2;
  const float* ikn_hb = ikn + (size_t)hb * CN + nt * 64;
#pragma unroll
  for (int p = 0; p < 2; p++) {
    int c = (tid & 3) + 4 * p;   // n-chunk
    u16 tk[8], tv[8], th[8];
#pragma unroll
    for (int j = 0; j < 8; j++) {
      tk[j] = Tk[(c * 8 + j) * 72 + d];
      tv[j] = Tv[(c * 8 + j) * 72 + d];
      th[j] = f2bf(bf2f(tv[j]) * ikn_hb[c * 8 + j]);
    }
    size_t dst = (((size_t)hb * 64 + d) * CN) + nt * 64 + c * 8;
    *(bf16x8*)&fkT[dst] = *(bf16x8*)tk;
    *(bf16x8*)&fvT[dst] = *(bf16x8*)tv;
    *(bf16x8*)&fvhT[dst] = *(bf16x8*)th;
  }
}

// ---------------------------------------------------------------------------
// K3a: gemm_M — per (h,b): M1 = K^T V_hat, M2 = K^T V (each 64x64), m-split 4.
// grid 64 (hb:4 low | ms:2), 256 threads, double-buffered staging.
// Mpart[(hb*4+ms)][j=mat*64+i][d] f32.
// ---------------------------------------------------------------------------
__global__ __launch_bounds__(256) void gemm_M(const u16* __restrict__ fkT,
                                              const u16* __restrict__ fvT,
                                              const u16* __restrict__ fvhT,
                                              float* __restrict__ Mpart) {
  int bid = blockIdx.x;
  int hb = bid & 15, ms = bid >> 4;   // ms in [0,4)
  int tid = threadIdx.x, w = tid >> 6, l = tid & 63;
  int lo = l & 15, hi = l >> 4;

  __shared__ u16 Ak[2][64 * 64];
  __shared__ u16 Bv[2][64 * 64];
  __shared__ u16 Bh[2][64 * 64];

  const u16* Ab = fkT + (size_t)hb * 64 * CN;
  const u16* Vb = fvT + (size_t)hb * 64 * CN;
  const u16* Hb = fvhT + (size_t)hb * 64 * CN;

  f32x4 zz = {0.f, 0.f, 0.f, 0.f};
  f32x4 acc[2][4];
#pragma unroll
  for (int mat = 0; mat < 2; mat++)
#pragma unroll
    for (int dt = 0; dt < 4; dt++) acc[mat][dt] = zz;

  int rls = 8 * w + (l >> 3);
  int sls = l & 7;

  auto STAGE = [&](int kt, int slot) {
    int mc = ms * 512 + kt * 64;
#pragma unroll
    for (int i = 0; i < 2; i++) {
      int row = rls + 32 * i;
      int sp = sls ^ (row & 7);
      GLOAD16(Ab + (size_t)row * CN + mc + sp * 8, (char*)Ak[slot] + w * 1024 + i * 4096);
      GLOAD16(Vb + (size_t)row * CN + mc + sp * 8, (char*)Bv[slot] + w * 1024 + i * 4096);
      GLOAD16(Hb + (size_t)row * CN + mc + sp * 8, (char*)Bh[slot] + w * 1024 + i * 4096);
    }
  };

  STAGE(0, 0);
  __syncthreads();

  int cur = 0;
  for (int kt = 0; kt < 8; ++kt) {
    if (kt + 1 < 8) STAGE(kt + 1, cur ^ 1);
#pragma unroll
    for (int kk = 0; kk < 2; kk++) {
      int arow = w * 16 + lo;
      int aslot = (hi + 4 * kk) ^ (arow & 7);
      bf16x8 af = *(const bf16x8*)&Ak[cur][arow * 64 + aslot * 8];
#pragma unroll
      for (int dt = 0; dt < 4; dt++) {
        int brow = dt * 16 + lo;
        int bslot = (hi + 4 * kk) ^ (brow & 7);
        bf16x8 bh = *(const bf16x8*)&Bh[cur][brow * 64 + bslot * 8];
        bf16x8 bv = *(const bf16x8*)&Bv[cur][brow * 64 + bslot * 8];
        acc[0][dt] = MFMA(af, bh, acc[0][dt]);   // M1 (scaled V)
        acc[1][dt] = MFMA(af, bv, acc[1][dt]);   // M2
      }
    }
    if (kt + 1 < 8) {
      __syncthreads();
      cur ^= 1;
    }
  }

  float* outp = Mpart + ((size_t)(hb * 4 + ms)) * 8192;
#pragma unroll
  for (int mat = 0; mat < 2; mat++)
#pragma unroll
    for (int dt = 0; dt < 4; dt++) {
      int d = dt * 16 + lo;
#pragma unroll
      for (int rg = 0; rg < 4; rg++) {
        int j = mat * 64 + w * 16 + hi * 4 + rg;
        outp[j * 64 + d] = acc[mat][dt][rg];
      }
    }
}

// ---------------------------------------------------------------------------
// K3b: reduceM_mlp — per hb: (1) reduce qgp/kgp + blend-MLP -> alpha/beta/gamma
// (redundant per block, trivial); (2) sum 4 m-split partials, fold rank-1,
// write Bmat[hb][jrow][icol] bf16.  grid 16, 256 thr.
// ---------------------------------------------------------------------------
__global__ __launch_bounds__(256) void reduceM_mlp(const float* __restrict__ Mpart,
                                                   const float* __restrict__ qgp,
                                                   const float* __restrict__ kgp,
                                                   const float* __restrict__ w1,
                                                   const float* __restrict__ b1,
                                                   const float* __restrict__ lng,
                                                   const float* __restrict__ lnb,
                                                   const float* __restrict__ w2,
                                                   const float* __restrict__ b2,
                                                   u16* __restrict__ Bmat) {
  int hb = blockIdx.x;
  int h = hb >> 1;
  int tid = threadIdx.x;
  __shared__ float qg[64], kg[64], abg[3];
  if (tid < 64) {
    float s1 = 0.f, s2 = 0.f;
#pragma unroll
    for (int c = 0; c < 32; c++) {
      s1 += qgp[(c * 8 + h) * 64 + tid];
      s2 += kgp[(c * 8 + h) * 64 + tid];
    }
    qg[tid] = s1 * (1.f / 4096.f);
    kg[tid] = s2 * (1.f / 4096.f);
  }
  __syncthreads();
  if (tid < 64) {
    float acc = b1[tid];
#pragma unroll 8
    for (int i = 0; i < 64; i++)
      acc += qg[i] * w1[tid * 128 + i] + kg[i] * w1[tid * 128 + 64 + i];
    float s1 = acc, s2 = acc * acc;
#pragma unroll
    for (int m = 1; m < 64; m <<= 1) { s1 += __shfl_xor(s1, m); s2 += __shfl_xor(s2, m); }
    float mean = s1 * (1.f / 64.f);
    float var = s2 * (1.f / 64.f) - mean * mean;
    float y = (acc - mean) * rsqrtf(var + 1e-5f) * lng[tid] + lnb[tid];
    float hid = fmaxf(y, 0.f);
    float t = hid * w2[tid];
#pragma unroll
    for (int m = 1; m < 64; m <<= 1) t += __shfl_xor(t, m);
    float wv = 1.f / (1.f + expf(-(t + b2[0])));
    if (tid == 0) { abg[0] = 1.f - wv; abg[1] = wv * (1.f / 64.f); abg[2] = wv; }
  }
  __syncthreads();
  float alpha = abg[0], beta = abg[1], gamma = abg[2];

  __shared__ float Ms[128 * 65];
  __shared__ float S2s[64];
#pragma unroll
  for (int e = 0; e < 32; e++) {
    int idx = e * 256 + tid;
    int j = idx >> 6, d = idx & 63;
    float s = 0.f;
#pragma unroll
    for (int ms = 0; ms < 4; ms++)
      s += Mpart[((size_t)(hb * 4 + ms)) * 8192 + idx];
    Ms[j * 65 + d] = s;
  }
  __syncthreads();
  if (tid < 64) {
    float s = 0.f;
#pragma unroll
    for (int i = 0; i < 64; i++) s += Ms[(64 + i) * 65 + tid];
    S2s[tid] = s;
  }
  __syncthreads();
#pragma unroll
  for (int e = 0; e < 32; e++) {
    int idx = e * 256 + tid;
    int jr = idx >> 6, ic = idx & 63;
    float v;
    if (jr < 64) v = alpha * Ms[ic * 65 + jr];
    else {
      int d = jr - 64;
      v = beta * Ms[(64 + ic) * 65 + d] - (gamma * (1.f / 4096.f)) * S2s[d];
    }
    Bmat[(size_t)hb * 8192 + idx] = f2bf(v);
  }
}

// ---------------------------------------------------------------------------
// K3c: gemm_out — out[n] = iqn[n]*(fq@aM1) + fq@(bM2 - rank1)  -> A2 bf16.
// grid 256 (hb*16+qt), 256 threads (4 waves), no LDS, no barriers.
// ---------------------------------------------------------------------------
__global__ __launch_bounds__(256) void gemm_out(const u16* __restrict__ F0,
                                                const u16* __restrict__ Bmat,
                                                const float* __restrict__ iqn,
                                                u16* __restrict__ A2) {
  int bid = blockIdx.x;
  int hb = bid >> 4, qt = bid & 15;
  int b = hb & 1, h = hb >> 1;
  int tid = threadIdx.x, w = tid >> 6, l = tid & 63;
  int lo = l & 15, hi = l >> 4;
  int qbase = qt * 128;

  const u16* Bm = Bmat + (size_t)hb * 8192;
  bf16x8 bm[8][2];
#pragma unroll
  for (int jt = 0; jt < 8; jt++)
#pragma unroll
    for (int kk = 0; kk < 2; kk++)
      bm[jt][kk] = *(const bf16x8*)&Bm[(jt * 16 + lo) * 64 + hi * 8 + kk * 32];

  f32x4 zz = {0.f, 0.f, 0.f, 0.f};
  f32x4 acc[2][8];
#pragma unroll
  for (int f = 0; f < 2; f++)
#pragma unroll
    for (int jt = 0; jt < 8; jt++) acc[f][jt] = zz;

#pragma unroll
  for (int f = 0; f < 2; f++) {
    const u16* qp = F0 + ((size_t)(b * CN + qbase + w * 32 + f * 16 + lo)) * CD +
                    h * 64 + hi * 8;
    bf16x8 a0 = *(const bf16x8*)qp;
    bf16x8 a1 = *(const bf16x8*)(qp + 32);
#pragma unroll
    for (int jt = 0; jt < 8; jt++) {
      acc[f][jt] = MFMA(a0, bm[jt][0], acc[f][jt]);
      acc[f][jt] = MFMA(a1, bm[jt][1], acc[f][jt]);
    }
  }

  const float* iqn_hb = iqn + (size_t)hb * CN;
#pragma unroll
  for (int f = 0; f < 2; f++) {
    float iqv[4];
    int nb = qbase + w * 32 + f * 16 + hi * 4;
#pragma unroll
    for (int rg = 0; rg < 4; rg++) iqv[rg] = iqn_hb[nb + rg];
#pragma unroll
    for (int jt = 0; jt < 4; jt++) {
      int d = jt * 16 + lo;
#pragma unroll
      for (int rg = 0; rg < 4; rg++) {
        float vout = iqv[rg] * acc[f][jt][rg] + acc[f][jt + 4][rg];
        int n = nb + rg;
        A2[((size_t)(b * CN + n)) * CD + h * 64 + d] = f2bf(vout);
      }
    }
  }
}

// ---------------------------------------------------------------------------
extern "C" void kernel_launch(void* const* d_in, const int* in_sizes, int n_in,
                              void* d_out, int out_size, void* d_ws, size_t ws_size,
                              hipStream_t stream) {
  const float* q = (const float*)d_in[0];
  const float* k = (const float*)d_in[1];
  const float* v = (const float*)d_in[2];
  const float* ln_g = (const float*)d_in[3];
  const float* ln_b = (const float*)d_in[4];
  const float* W_in = (const float*)d_in[5];
  const float* wp_w1 = (const float*)d_in[6];
  const float* wp_b1 = (const float*)d_in[7];
  const float* wp_lng = (const float*)d_in[8];
  const float* wp_lnb = (const float*)d_in[9];
  const float* wp_w2 = (const float*)d_in[10];
  const float* wp_b2 = (const float*)d_in[11];
  const float* W_out = (const float*)d_in[12];
  const float* b_out = (const float*)d_in[13];

  char* ws = (char*)d_ws;
  u16* xln = (u16*)(ws + 0);              // 12,582,912 B
  u16* F = (u16*)(ws + 12582912);         // 12,582,912 B  [3][B][N][512]
  u16* Wi = (u16*)(ws + 25165824);        // 524,288 B
  u16* Wo = (u16*)(ws + 25690112);        // 524,288 B
  u16* fkT = (u16*)(ws + 26214400);       // 4,194,304 B   [HB][64][2048]
  u16* fvT = (u16*)(ws + 30408704);       // 4,194,304 B
  u16* fvhT = (u16*)(ws + 34603008);      // 4,194,304 B
  u16* A2 = (u16*)(ws + 38797312);        // 4,194,304 B   [B][N][512]
  float* iqn = (float*)(ws + 42991616);   // 131,072 B
  float* ikn = (float*)(ws + 43122688);   // 131,072 B
  float* qgp = (float*)(ws + 43253760);   // 65,536 B
  float* kgp = (float*)(ws + 43319296);   // 65,536 B
  float* Mpart = (float*)(ws + 43384832); // 2,097,152 B   [64][128][64] f32
  u16* Bmat = (u16*)(ws + 45481984);      // 262,144 B     [16][128][64] bf16

  u16* F0 = F;
  u16* F1 = F + 2097152;
  u16* F2 = F + 4194304;

  ln_convw_kernel<<<13312, 256, 0, stream>>>(q, k, v, ln_g, ln_b, xln,
                                             W_in, W_out, Wi, Wo);
  gemm_bt<1, 0, 1><<<dim3(96, 4), 256, 0, stream>>>(xln, Wi, (void*)F, nullptr,
                                                    iqn, ikn, qgp, kgp);
  transpose_kv<<<512, 256, 0, stream>>>(F1, F2, ikn, fkT, fvT, fvhT);
  gemm_M<<<64, 256, 0, stream>>>(fkT, fvT, fvhT, Mpart);
  reduceM_mlp<<<16, 256, 0, stream>>>(Mpart, qgp, kgp, wp_w1, wp_b1,
                                      wp_lng, wp_lnb, wp_w2, wp_b2, Bmat);
  gemm_out<<<256, 256, 0, stream>>>(F0, Bmat, iqn, A2);
  gemm_bt<0, 1, 0><<<dim3(32, 4), 256, 0, stream>>>(A2, Wo, d_out, b_out,
                                                    nullptr, nullptr, nullptr, nullptr);
}

// Round 11
// 61.542 us; speedup vs baseline: 1.7031x; 1.1716x over previous
//
#include <hip/hip_runtime.h>
#include <stdint.h>

// Problem constants
#define CH 8      // heads
#define CDH 64    // dim head
#define CB 2      // batch
#define CN 2048   // seq
#define CD 512    // model dim

typedef float f32x4 __attribute__((ext_vector_type(4)));
typedef __bf16 bf16x8 __attribute__((ext_vector_type(8)));
typedef unsigned short u16;
typedef unsigned int u32;

#define MFMA(a, b, c) __builtin_amdgcn_mfma_f32_16x16x32_bf16((a), (b), (c), 0, 0, 0)
#define GLOAD16(g, l)                                                              \
  __builtin_amdgcn_global_load_lds((const __attribute__((address_space(1))) void*)(g), \
                                   (__attribute__((address_space(3))) void*)(l), 16, 0, 0)

__device__ __forceinline__ u16 f2bf(float f) {
  union { float f; unsigned u; } c; c.f = f;
  return (u16)((c.u + 0x7FFFu + ((c.u >> 16) & 1u)) >> 16);
}
__device__ __forceinline__ float bf2f(u16 h) {
  union { unsigned u; float f; } c; c.u = ((unsigned)h) << 16;
  return c.f;
}

// ---------------------------------------------------------------------------
// K0: LayerNorm for q,k,v -> xln bf16 [3*4096][512]; tail blocks convert W
// grid 13312 = 12288 LN + 1024 conv
// ---------------------------------------------------------------------------
__global__ __launch_bounds__(256) void ln_convw_kernel(const float* __restrict__ q,
                                                       const float* __restrict__ k,
                                                       const float* __restrict__ v,
                                                       const float* __restrict__ g,
                                                       const float* __restrict__ bb,
                                                       u16* __restrict__ xln,
                                                       const float* __restrict__ wi_f,
                                                       const float* __restrict__ wo_f,
                                                       u16* __restrict__ wi,
                                                       u16* __restrict__ wo) {
  int row = blockIdx.x;
  int tid = threadIdx.x;
  if (row >= 12288) {
    int i = (row - 12288) * 256 + tid;   // < 262144
    wi[i] = f2bf(wi_f[i]);
    wo[i] = f2bf(wo_f[i]);
    return;
  }
  int t = row >> 12;
  int rr = row & 4095;
  const float* src = (t == 0 ? q : (t == 1 ? k : v)) + (size_t)rr * CD;
  float x0 = src[tid], x1 = src[tid + 256];
  float s = x0 + x1, s2 = x0 * x0 + x1 * x1;
#pragma unroll
  for (int m = 1; m < 64; m <<= 1) { s += __shfl_xor(s, m); s2 += __shfl_xor(s2, m); }
  __shared__ float red[8];
  int w = tid >> 6;
  if ((tid & 63) == 0) { red[w] = s; red[4 + w] = s2; }
  __syncthreads();
  s = red[0] + red[1] + red[2] + red[3];
  s2 = red[4] + red[5] + red[6] + red[7];
  float mean = s * (1.f / 512.f);
  float var = s2 * (1.f / 512.f) - mean * mean;
  float rstd = rsqrtf(var + 1e-5f);
  u16* dst = xln + (size_t)row * CD;
  dst[tid]       = f2bf((x0 - mean) * rstd * g[tid] + bb[tid]);
  dst[tid + 256] = f2bf((x1 - mean) * rstd * g[tid + 256] + bb[tid + 256]);
}

// ---------------------------------------------------------------------------
// Generic C = A * Bt^T bf16 MFMA GEMM, K=512, BM=BN=128, BK=64, dbuf.
// MODE=1 (gemm1): tblk<32 = q rows -> write F0 + iqn/qgp stats.
//                 tblk 32..63 = k -> NO C write; transpose to fkT + ikn/kgp.
//                 tblk 64..95 = v -> NO C write; transpose to fvT.
// MODE=0 (gemm2): plain C = A Bt^T + bias (f32 out).
// ---------------------------------------------------------------------------
template <int OUT_BF16, int ADD_BIAS, int MODE>
__global__ __launch_bounds__(256) void gemm_bt(const u16* __restrict__ A,
                                               const u16* __restrict__ Bt,
                                               void* __restrict__ Cout,
                                               const float* __restrict__ bias,
                                               float* __restrict__ iqn,
                                               float* __restrict__ ikn,
                                               float* __restrict__ qgp,
                                               float* __restrict__ kgp,
                                               u16* __restrict__ fkT,
                                               u16* __restrict__ fvT) {
  __shared__ u16 S[4][8192];   // Al = S[0..1], Bl = S[2..3]; reused by epilogue
#define AL_(s) (S[s])
#define BL_(s) (S[2 + (s)])
  int tm = blockIdx.x * 128, tn = blockIdx.y * 128;
  int tid = threadIdx.x;
  int w = tid >> 6, l = tid & 63;
  int wr = w >> 1, wc = w & 1;
  int lo = l & 15, hi = l >> 4;

  f32x4 zz = {0.f, 0.f, 0.f, 0.f};
  f32x4 acc[4][4];
#pragma unroll
  for (int mi = 0; mi < 4; mi++)
#pragma unroll
    for (int ni = 0; ni < 4; ni++) acc[mi][ni] = zz;

  int rowA = 8 * w + (l >> 3);
  int sl = l & 7;

#pragma unroll
  for (int i = 0; i < 4; i++) {
    int rl = rowA + 32 * i;
    int sp = sl ^ (rl & 7);
    GLOAD16(A + (size_t)(tm + rl) * CD + sp * 8, (char*)AL_(0) + w * 1024 + i * 4096);
    GLOAD16(Bt + (size_t)(tn + rl) * CD + sp * 8, (char*)BL_(0) + w * 1024 + i * 4096);
  }
  __syncthreads();

  int cur = 0;
  for (int kt = 0; kt < 8; ++kt) {
    if (kt + 1 < 8) {
      int nxt = cur ^ 1;
#pragma unroll
      for (int i = 0; i < 4; i++) {
        int rl = rowA + 32 * i;
        int sp = sl ^ (rl & 7);
        GLOAD16(A + (size_t)(tm + rl) * CD + (kt + 1) * 64 + sp * 8,
                (char*)AL_(nxt) + w * 1024 + i * 4096);
        GLOAD16(Bt + (size_t)(tn + rl) * CD + (kt + 1) * 64 + sp * 8,
                (char*)BL_(nxt) + w * 1024 + i * 4096);
      }
    }
    const u16* Ac = AL_(cur);
    const u16* Bc = BL_(cur);
#pragma unroll
    for (int kk = 0; kk < 2; kk++) {
      bf16x8 af[4], bfr[4];
#pragma unroll
      for (int mi = 0; mi < 4; mi++) {
        int row = wr * 64 + mi * 16 + lo;
        int slot = (hi + 4 * kk) ^ (row & 7);
        af[mi] = *(const bf16x8*)&Ac[row * 64 + slot * 8];
      }
#pragma unroll
      for (int ni = 0; ni < 4; ni++) {
        int row = wc * 64 + ni * 16 + lo;
        int slot = (hi + 4 * kk) ^ (row & 7);
        bfr[ni] = *(const bf16x8*)&Bc[row * 64 + slot * 8];
      }
#pragma unroll
      for (int mi = 0; mi < 4; mi++)
#pragma unroll
        for (int ni = 0; ni < 4; ni++)
          acc[mi][ni] = MFMA(af[mi], bfr[ni], acc[mi][ni]);
    }
    if (kt + 1 < 8) {
      __syncthreads();
      cur ^= 1;
    }
  }

  if (MODE == 1) {
    int tblk = blockIdx.x;
    int h = blockIdx.y * 2 + wc;
    if (tblk < 32) {
      // ---- q rows: iqn + qgp stats, then fall through to C write (F0) ----
#pragma unroll
      for (int mi = 0; mi < 4; mi++)
#pragma unroll
        for (int rg = 0; rg < 4; rg++) {
          float s2 = 0.f;
#pragma unroll
          for (int ni = 0; ni < 4; ni++) {
            float vv = acc[mi][ni][rg];
            s2 += vv * vv;
          }
#pragma unroll
          for (int m = 1; m < 16; m <<= 1) s2 += __shfl_xor(s2, m);
          if (lo == 0) {
            int rloc = tm + wr * 64 + mi * 16 + hi * 4 + rg;
            int b = rloc >> 11, n = rloc & 2047;
            iqn[((size_t)h * 2 + b) * CN + n] = rsqrtf(s2);
          }
        }
      float cs[4];
#pragma unroll
      for (int ni = 0; ni < 4; ni++) {
        float s = 0.f;
#pragma unroll
        for (int mi = 0; mi < 4; mi++)
#pragma unroll
          for (int rg = 0; rg < 4; rg++) s += acc[mi][ni][rg];
        s += __shfl_xor(s, 16);
        s += __shfl_xor(s, 32);
        cs[ni] = s;
      }
      __syncthreads();
      float* redl = (float*)&S[0][0];
      if (hi == 0)
#pragma unroll
        for (int ni = 0; ni < 4; ni++) redl[((wr * 2 + wc) * 4 + ni) * 16 + lo] = cs[ni];
      __syncthreads();
      if (wr == 0 && hi == 0) {
#pragma unroll
        for (int ni = 0; ni < 4; ni++) {
          float vsum = redl[((0 * 2 + wc) * 4 + ni) * 16 + lo] +
                       redl[((1 * 2 + wc) * 4 + ni) * 16 + lo];
          qgp[(tblk * 8 + h) * 64 + ni * 16 + lo] = vsum;
        }
      }
      // fall through to C write
    } else {
      // ---- k/v rows: transpose to fkT/fvT; k also ikn + kgp; no C write ----
      bool isk = tblk < 64;
      u16* dstT = isk ? fkT : fvT;
      int rloc0 = tm - (isk ? 4096 : 8192);
      int bb2 = rloc0 >> 11, n0 = rloc0 & 2047;
      float csk[4];
      if (isk) {
#pragma unroll
        for (int mi = 0; mi < 4; mi++)
#pragma unroll
          for (int rg = 0; rg < 4; rg++) {
            float s2 = 0.f;
#pragma unroll
            for (int ni = 0; ni < 4; ni++) {
              float vv = acc[mi][ni][rg];
              s2 += vv * vv;
            }
#pragma unroll
            for (int m = 1; m < 16; m <<= 1) s2 += __shfl_xor(s2, m);
            if (lo == 0) {
              int n = n0 + wr * 64 + mi * 16 + hi * 4 + rg;
              ikn[((size_t)h * 2 + bb2) * CN + n] = rsqrtf(s2);
            }
          }
#pragma unroll
        for (int ni = 0; ni < 4; ni++) {
          float s = 0.f;
#pragma unroll
          for (int mi = 0; mi < 4; mi++)
#pragma unroll
            for (int rg = 0; rg < 4; rg++) s += acc[mi][ni][rg];
          s += __shfl_xor(s, 16);
          s += __shfl_xor(s, 32);
          csk[ni] = s;
        }
      }
      __syncthreads();   // all waves done reading S (MFMA operands)
      // transpose acc -> S: region reg = wc*2+wr holds [64 d][64 m'] swizzled
      u16* Sf = &S[0][0];
      int reg = wc * 2 + wr;
#pragma unroll
      for (int mi = 0; mi < 4; mi++)
#pragma unroll
        for (int ni = 0; ni < 4; ni++) {
          int d = ni * 16 + lo;
          int m0 = mi * 16 + hi * 4;
          u16 t4[4];
#pragma unroll
          for (int rg = 0; rg < 4; rg++) t4[rg] = f2bf(acc[mi][ni][rg]);
          int off = (reg * 64 + d) * 64 + (m0 ^ ((d & 7) << 3));
          *(uint2*)&Sf[off] = *(const uint2*)t4;
        }
      __syncthreads();
      // coalesced global write: head = tid>>7, 8 passes
      {
        int head = tid >> 7, c = tid & 127;
        int hg = blockIdx.y * 2 + head;
        size_t base = ((size_t)(hg * 2 + bb2)) * 64 * CN;
#pragma unroll
        for (int p = 0; p < 8; p++) {
          int flat = p * 128 + c;
          int d = flat >> 4, mc = flat & 15;
          int wr2 = mc >> 3, m64 = (mc & 7) * 8;
          int off = ((head * 2 + wr2) * 64 + d) * 64 + (m64 ^ ((d & 7) << 3));
          bf16x8 vv = *(const bf16x8*)&Sf[off];
          *(bf16x8*)&dstT[base + (size_t)d * CN + n0 + mc * 8] = vv;
        }
      }
      if (isk) {
        __syncthreads();
        float* redl = (float*)&S[0][0];
        if (hi == 0)
#pragma unroll
          for (int ni = 0; ni < 4; ni++) redl[((wr * 2 + wc) * 4 + ni) * 16 + lo] = csk[ni];
        __syncthreads();
        if (wr == 0 && hi == 0) {
#pragma unroll
          for (int ni = 0; ni < 4; ni++) {
            float vsum = redl[((0 * 2 + wc) * 4 + ni) * 16 + lo] +
                         redl[((1 * 2 + wc) * 4 + ni) * 16 + lo];
            kgp[((tblk - 32) * 8 + h) * 64 + ni * 16 + lo] = vsum;
          }
        }
      }
      return;   // no C write for k/v blocks
    }
  }

#pragma unroll
  for (int mi = 0; mi < 4; mi++)
#pragma unroll
    for (int ni = 0; ni < 4; ni++) {
      int col = tn + wc * 64 + ni * 16 + lo;
      float bv = ADD_BIAS ? bias[col] : 0.f;
#pragma unroll
      for (int rg = 0; rg < 4; rg++) {
        int rowg = tm + wr * 64 + mi * 16 + hi * 4 + rg;
        float vout = acc[mi][ni][rg] + bv;
        if (OUT_BF16)
          ((u16*)Cout)[(size_t)rowg * CD + col] = f2bf(vout);
        else
          ((float*)Cout)[(size_t)rowg * CD + col] = vout;
      }
    }
#undef AL_
#undef BL_
}

// ---------------------------------------------------------------------------
// K3a: gemm_M — per (h,b): M1 = (K*ikn)^T V, M2 = K^T V (64x64 each), m-split 4.
// grid 64 (hb:4 low | ms:2), 256 threads. Ak,Bv via global_load_lds; Akh
// reg-staged (load->scale by ikn[m]->ds_write) hidden under MFMA (T14).
// Mpart[(hb*4+ms)][j=mat*64+i][d] f32.
// ---------------------------------------------------------------------------
__global__ __launch_bounds__(256) void gemm_M(const u16* __restrict__ fkT,
                                              const u16* __restrict__ fvT,
                                              const float* __restrict__ ikn,
                                              float* __restrict__ Mpart) {
  int bid = blockIdx.x;
  int hb = bid & 15, ms = bid >> 4;   // ms in [0,4)
  int tid = threadIdx.x, w = tid >> 6, l = tid & 63;
  int lo = l & 15, hi = l >> 4;

  __shared__ u16 GM[6][4096];   // Ak[2], Akh[2], Bv[2]
#define AK_(s) (GM[s])
#define AKH_(s) (GM[2 + (s)])
#define BV_(s) (GM[4 + (s)])

  const u16* Ab = fkT + (size_t)hb * 64 * CN;
  const u16* Vb = fvT + (size_t)hb * 64 * CN;
  const float* ikb = ikn + (size_t)hb * CN;

  f32x4 zz = {0.f, 0.f, 0.f, 0.f};
  f32x4 acc[2][4];
#pragma unroll
  for (int mat = 0; mat < 2; mat++)
#pragma unroll
    for (int dt = 0; dt < 4; dt++) acc[mat][dt] = zz;

  int rls = 8 * w + (l >> 3);
  int sls = l & 7;

  bf16x8 areg[2];
  f32x4 ikreg[2][2];

  auto STAGEGL = [&](int kt, int slot) {
    int mc = ms * 512 + kt * 64;
#pragma unroll
    for (int i = 0; i < 2; i++) {
      int row = rls + 32 * i;
      int sp = sls ^ (row & 7);
      GLOAD16(Ab + (size_t)row * CN + mc + sp * 8, (char*)AK_(slot) + w * 1024 + i * 4096);
      GLOAD16(Vb + (size_t)row * CN + mc + sp * 8, (char*)BV_(slot) + w * 1024 + i * 4096);
    }
  };
  auto LOADA = [&](int kt) {
    int mc = ms * 512 + kt * 64;
#pragma unroll
    for (int i = 0; i < 2; i++) {
      int row = rls + 32 * i;
      int sp = sls ^ (row & 7);
      areg[i] = *(const bf16x8*)&Ab[(size_t)row * CN + mc + sp * 8];
      ikreg[i][0] = *(const f32x4*)&ikb[mc + sp * 8];
      ikreg[i][1] = *(const f32x4*)&ikb[mc + sp * 8 + 4];
    }
  };
  auto WRITEA = [&](int slot) {
#pragma unroll
    for (int i = 0; i < 2; i++) {
      u16 outp[8];
#pragma unroll
      for (int j = 0; j < 4; j++) outp[j] = f2bf((float)areg[i][j] * ikreg[i][0][j]);
#pragma unroll
      for (int j = 0; j < 4; j++) outp[4 + j] = f2bf((float)areg[i][4 + j] * ikreg[i][1][j]);
      *(bf16x8*)((char*)AKH_(slot) + w * 1024 + i * 4096 + l * 16) = *(const bf16x8*)outp;
    }
  };

  LOADA(0);
  STAGEGL(0, 0);
  WRITEA(0);
  __syncthreads();

  int cur = 0;
  for (int kt = 0; kt < 8; ++kt) {
    if (kt + 1 < 8) {
      LOADA(kt + 1);
      STAGEGL(kt + 1, cur ^ 1);
    }
#pragma unroll
    for (int kk = 0; kk < 2; kk++) {
      int arow = w * 16 + lo;
      int aslot = (hi + 4 * kk) ^ (arow & 7);
      bf16x8 af = *(const bf16x8*)&AK_(cur)[arow * 64 + aslot * 8];
      bf16x8 afh = *(const bf16x8*)&AKH_(cur)[arow * 64 + aslot * 8];
#pragma unroll
      for (int dt = 0; dt < 4; dt++) {
        int brow = dt * 16 + lo;
        int bslot = (hi + 4 * kk) ^ (brow & 7);
        bf16x8 bv = *(const bf16x8*)&BV_(cur)[brow * 64 + bslot * 8];
        acc[0][dt] = MFMA(afh, bv, acc[0][dt]);   // M1 (scaled K)
        acc[1][dt] = MFMA(af, bv, acc[1][dt]);    // M2
      }
    }
    if (kt + 1 < 8) {
      WRITEA(cur ^ 1);
      __syncthreads();
      cur ^= 1;
    }
  }

  float* outp = Mpart + ((size_t)(hb * 4 + ms)) * 8192;
#pragma unroll
  for (int mat = 0; mat < 2; mat++)
#pragma unroll
    for (int dt = 0; dt < 4; dt++) {
      int d = dt * 16 + lo;
#pragma unroll
      for (int rg = 0; rg < 4; rg++) {
        int j = mat * 64 + w * 16 + hi * 4 + rg;
        outp[j * 64 + d] = acc[mat][dt][rg];
      }
    }
#undef AK_
#undef AKH_
#undef BV_
}

// ---------------------------------------------------------------------------
// K3b: reduceM_mlp — per hb: (1) reduce qgp/kgp + blend-MLP -> alpha/beta/gamma
// (redundant per block); (2) sum 4 m-split partials, fold rank-1, write
// Bmat[hb][jrow][icol] bf16.  grid 16, 256 thr.
// ---------------------------------------------------------------------------
__global__ __launch_bounds__(256) void reduceM_mlp(const float* __restrict__ Mpart,
                                                   const float* __restrict__ qgp,
                                                   const float* __restrict__ kgp,
                                                   const float* __restrict__ w1,
                                                   const float* __restrict__ b1,
                                                   const float* __restrict__ lng,
                                                   const float* __restrict__ lnb,
                                                   const float* __restrict__ w2,
                                                   const float* __restrict__ b2,
                                                   u16* __restrict__ Bmat) {
  int hb = blockIdx.x;
  int h = hb >> 1;
  int tid = threadIdx.x;
  __shared__ float qg[64], kg[64], abg[3];
  if (tid < 64) {
    float s1 = 0.f, s2 = 0.f;
#pragma unroll
    for (int c = 0; c < 32; c++) {
      s1 += qgp[(c * 8 + h) * 64 + tid];
      s2 += kgp[(c * 8 + h) * 64 + tid];
    }
    qg[tid] = s1 * (1.f / 4096.f);
    kg[tid] = s2 * (1.f / 4096.f);
  }
  __syncthreads();
  if (tid < 64) {
    float acc = b1[tid];
#pragma unroll 8
    for (int i = 0; i < 64; i++)
      acc += qg[i] * w1[tid * 128 + i] + kg[i] * w1[tid * 128 + 64 + i];
    float s1 = acc, s2 = acc * acc;
#pragma unroll
    for (int m = 1; m < 64; m <<= 1) { s1 += __shfl_xor(s1, m); s2 += __shfl_xor(s2, m); }
    float mean = s1 * (1.f / 64.f);
    float var = s2 * (1.f / 64.f) - mean * mean;
    float y = (acc - mean) * rsqrtf(var + 1e-5f) * lng[tid] + lnb[tid];
    float hid = fmaxf(y, 0.f);
    float t = hid * w2[tid];
#pragma unroll
    for (int m = 1; m < 64; m <<= 1) t += __shfl_xor(t, m);
    float wv = 1.f / (1.f + expf(-(t + b2[0])));
    if (tid == 0) { abg[0] = 1.f - wv; abg[1] = wv * (1.f / 64.f); abg[2] = wv; }
  }
  __syncthreads();
  float alpha = abg[0], beta = abg[1], gamma = abg[2];

  __shared__ float Ms[128 * 65];
  __shared__ float S2s[64];
#pragma unroll
  for (int e = 0; e < 32; e++) {
    int idx = e * 256 + tid;
    int j = idx >> 6, d = idx & 63;
    float s = 0.f;
#pragma unroll
    for (int ms = 0; ms < 4; ms++)
      s += Mpart[((size_t)(hb * 4 + ms)) * 8192 + idx];
    Ms[j * 65 + d] = s;
  }
  __syncthreads();
  if (tid < 64) {
    float s = 0.f;
#pragma unroll
    for (int i = 0; i < 64; i++) s += Ms[(64 + i) * 65 + tid];
    S2s[tid] = s;
  }
  __syncthreads();
#pragma unroll
  for (int e = 0; e < 32; e++) {
    int idx = e * 256 + tid;
    int jr = idx >> 6, ic = idx & 63;
    float v;
    if (jr < 64) v = alpha * Ms[ic * 65 + jr];
    else {
      int d = jr - 64;
      v = beta * Ms[(64 + ic) * 65 + d] - (gamma * (1.f / 4096.f)) * S2s[d];
    }
    Bmat[(size_t)hb * 8192 + idx] = f2bf(v);
  }
}

// ---------------------------------------------------------------------------
// K3c: gemm_out — out[n] = iqn[n]*(fq@aM1) + fq@(bM2 - rank1)  -> A2 bf16.
// grid 256 (hb*16+qt), 256 threads (4 waves), no LDS, no barriers.
// ---------------------------------------------------------------------------
__global__ __launch_bounds__(256) void gemm_out(const u16* __restrict__ F0,
                                                const u16* __restrict__ Bmat,
                                                const float* __restrict__ iqn,
                                                u16* __restrict__ A2) {
  int bid = blockIdx.x;
  int hb = bid >> 4, qt = bid & 15;
  int b = hb & 1, h = hb >> 1;
  int tid = threadIdx.x, w = tid >> 6, l = tid & 63;
  int lo = l & 15, hi = l >> 4;
  int qbase = qt * 128;

  const u16* Bm = Bmat + (size_t)hb * 8192;
  bf16x8 bm[8][2];
#pragma unroll
  for (int jt = 0; jt < 8; jt++)
#pragma unroll
    for (int kk = 0; kk < 2; kk++)
      bm[jt][kk] = *(const bf16x8*)&Bm[(jt * 16 + lo) * 64 + hi * 8 + kk * 32];

  f32x4 zz = {0.f, 0.f, 0.f, 0.f};
  f32x4 acc[2][8];
#pragma unroll
  for (int f = 0; f < 2; f++)
#pragma unroll
    for (int jt = 0; jt < 8; jt++) acc[f][jt] = zz;

#pragma unroll
  for (int f = 0; f < 2; f++) {
    const u16* qp = F0 + ((size_t)(b * CN + qbase + w * 32 + f * 16 + lo)) * CD +
                    h * 64 + hi * 8;
    bf16x8 a0 = *(const bf16x8*)qp;
    bf16x8 a1 = *(const bf16x8*)(qp + 32);
#pragma unroll
    for (int jt = 0; jt < 8; jt++) {
      acc[f][jt] = MFMA(a0, bm[jt][0], acc[f][jt]);
      acc[f][jt] = MFMA(a1, bm[jt][1], acc[f][jt]);
    }
  }

  const float* iqn_hb = iqn + (size_t)hb * CN;
#pragma unroll
  for (int f = 0; f < 2; f++) {
    float iqv[4];
    int nb = qbase + w * 32 + f * 16 + hi * 4;
#pragma unroll
    for (int rg = 0; rg < 4; rg++) iqv[rg] = iqn_hb[nb + rg];
#pragma unroll
    for (int jt = 0; jt < 4; jt++) {
      int d = jt * 16 + lo;
#pragma unroll
      for (int rg = 0; rg < 4; rg++) {
        float vout = iqv[rg] * acc[f][jt][rg] + acc[f][jt + 4][rg];
        int n = nb + rg;
        A2[((size_t)(b * CN + n)) * CD + h * 64 + d] = f2bf(vout);
      }
    }
  }
}

// ---------------------------------------------------------------------------
extern "C" void kernel_launch(void* const* d_in, const int* in_sizes, int n_in,
                              void* d_out, int out_size, void* d_ws, size_t ws_size,
                              hipStream_t stream) {
  const float* q = (const float*)d_in[0];
  const float* k = (const float*)d_in[1];
  const float* v = (const float*)d_in[2];
  const float* ln_g = (const float*)d_in[3];
  const float* ln_b = (const float*)d_in[4];
  const float* W_in = (const float*)d_in[5];
  const float* wp_w1 = (const float*)d_in[6];
  const float* wp_b1 = (const float*)d_in[7];
  const float* wp_lng = (const float*)d_in[8];
  const float* wp_lnb = (const float*)d_in[9];
  const float* wp_w2 = (const float*)d_in[10];
  const float* wp_b2 = (const float*)d_in[11];
  const float* W_out = (const float*)d_in[12];
  const float* b_out = (const float*)d_in[13];

  char* ws = (char*)d_ws;
  u16* xln = (u16*)(ws + 0);              // 12,582,912 B  [3*4096][512]
  u16* F0 = (u16*)(ws + 12582912);        // 4,194,304 B   [B*N][512] (q proj)
  u16* Wi = (u16*)(ws + 16777216);        // 524,288 B
  u16* Wo = (u16*)(ws + 17301504);        // 524,288 B
  u16* fkT = (u16*)(ws + 17825792);       // 4,194,304 B   [HB][64][2048]
  u16* fvT = (u16*)(ws + 22020096);       // 4,194,304 B
  u16* A2 = (u16*)(ws + 26214400);        // 4,194,304 B   [B][N][512]
  float* iqn = (float*)(ws + 30408704);   // 131,072 B
  float* ikn = (float*)(ws + 30539776);   // 131,072 B
  float* qgp = (float*)(ws + 30670848);   // 65,536 B
  float* kgp = (float*)(ws + 30736384);   // 65,536 B
  float* Mpart = (float*)(ws + 30801920); // 2,097,152 B   [64][128][64] f32
  u16* Bmat = (u16*)(ws + 32899072);      // 262,144 B     [16][128][64] bf16

  ln_convw_kernel<<<13312, 256, 0, stream>>>(q, k, v, ln_g, ln_b, xln,
                                             W_in, W_out, Wi, Wo);
  gemm_bt<1, 0, 1><<<dim3(96, 4), 256, 0, stream>>>(xln, Wi, (void*)F0, nullptr,
                                                    iqn, ikn, qgp, kgp, fkT, fvT);
  gemm_M<<<64, 256, 0, stream>>>(fkT, fvT, ikn, Mpart);
  reduceM_mlp<<<16, 256, 0, stream>>>(Mpart, qgp, kgp, wp_w1, wp_b1,
                                      wp_lng, wp_lnb, wp_w2, wp_b2, Bmat);
  gemm_out<<<256, 256, 0, stream>>>(F0, Bmat, iqn, A2);
  gemm_bt<0, 1, 0><<<dim3(32, 4), 256, 0, stream>>>(A2, Wo, d_out, b_out,
                                                    nullptr, nullptr, nullptr,
                                                    nullptr, nullptr, nullptr);
}